// Round 1
// baseline (24921.156 us; speedup 1.0000x reference)
//
#include <hip/hip_runtime.h>
#include <math.h>

#define B_SZ 2048
#define M_SZ 131072
#define E_SZ 256
#define K_SZ 128
#define V_SZ 256
#define O_SZ 256
#define NC   64                 // number of M chunks for partial top-3
#define MCHUNK (M_SZ / NC)      // 2048 keys per chunk
#define KT   64                 // keys per LDS tile

// workspace layout in floats
#define WS_QNT   0                           // qn transposed [K_SZ][B_SZ]
#define WS_RNK   (WS_QNT + K_SZ * B_SZ)      // [M_SZ]
#define WS_CVAL  (WS_RNK + M_SZ)             // [B_SZ][NC][3]
#define WS_CIDX  (WS_CVAL + B_SZ * NC * 3)   // int [B_SZ][NC][3]
#define WS_TVAL  (WS_CIDX + B_SZ * NC * 3)   // [B_SZ][3]
#define WS_TIDX  (WS_TVAL + B_SZ * 3)        // int [B_SZ][3]

#define NEG_INF (-3.0e38f)

#define TOP3_INS(v, m)                                            \
  do {                                                            \
    float _v = (v); int _m = (m);                                 \
    if (_v > tv2) {                                               \
      if (_v > tv1) {                                             \
        if (_v > tv0) {                                           \
          tv2 = tv1; ti2 = ti1; tv1 = tv0; ti1 = ti0;             \
          tv0 = _v; ti0 = _m;                                     \
        } else {                                                  \
          tv2 = tv1; ti2 = ti1; tv1 = _v; ti1 = _m;               \
        }                                                         \
      } else {                                                    \
        tv2 = _v; ti2 = _m;                                       \
      }                                                           \
    }                                                             \
  } while (0)

// ---------------------------------------------------------------------------
// Kernel 1: query = relu(state@k_w1+b1)@k_w2+b2, normalized; stored transposed
// 8 batch rows per 256-thread block.
// ---------------------------------------------------------------------------
__global__ void mann_encoder(const float* __restrict__ state,
                             const float* __restrict__ k_w1,
                             const float* __restrict__ k_b1,
                             const float* __restrict__ k_w2,
                             const float* __restrict__ k_b2,
                             float* __restrict__ qnT) {
  __shared__ float s_s[8][256];
  __shared__ float s_h[8][512];
  __shared__ float s_q[8][128];
  __shared__ float s_rn[8];
  const int t = threadIdx.x;
  const int b0 = blockIdx.x * 8;

#pragma unroll
  for (int i = 0; i < 8; ++i) {
    int idx = i * 256 + t;
    s_s[idx >> 8][idx & 255] = state[(size_t)b0 * E_SZ + idx];
  }
  __syncthreads();

  // hidden layer: thread t computes h[r][t] and h[r][t+256]
  float acc0[8], acc1[8];
  {
    float ba = k_b1[t], bb = k_b1[t + 256];
#pragma unroll
    for (int r = 0; r < 8; ++r) { acc0[r] = ba; acc1[r] = bb; }
  }
  for (int i = 0; i < 256; ++i) {
    float w0 = k_w1[i * 512 + t];
    float w1 = k_w1[i * 512 + t + 256];
#pragma unroll
    for (int r = 0; r < 8; ++r) {
      acc0[r] += s_s[r][i] * w0;
      acc1[r] += s_s[r][i] * w1;
    }
  }
#pragma unroll
  for (int r = 0; r < 8; ++r) {
    s_h[r][t] = fmaxf(acc0[r], 0.f);
    s_h[r][t + 256] = fmaxf(acc1[r], 0.f);
  }
  __syncthreads();

  // output layer: threads 0..127 compute q[r][t]
  if (t < 128) {
    float a[8];
    float b2 = k_b2[t];
#pragma unroll
    for (int r = 0; r < 8; ++r) a[r] = b2;
    for (int i = 0; i < 512; ++i) {
      float w = k_w2[i * 128 + t];
#pragma unroll
      for (int r = 0; r < 8; ++r) a[r] += s_h[r][i] * w;
    }
#pragma unroll
    for (int r = 0; r < 8; ++r) s_q[r][t] = a[r];
  }
  __syncthreads();

  if (t < 8) {
    float s = 0.f;
    for (int j = 0; j < 128; ++j) { float v = s_q[t][j]; s += v * v; }
    s_rn[t] = 1.0f / fmaxf(sqrtf(s), 1e-8f);
  }
  __syncthreads();

  if (t < 128) {
#pragma unroll
    for (int r = 0; r < 8; ++r)
      qnT[(size_t)t * B_SZ + (b0 + r)] = s_q[r][t] * s_rn[r];
  }
}

// ---------------------------------------------------------------------------
// Kernel 2: reciprocal key norms, one wave per key row
// ---------------------------------------------------------------------------
__global__ void mann_keynorm(const float* __restrict__ keys,
                             float* __restrict__ rnk) {
  const int lane = threadIdx.x & 63;
  const int row = blockIdx.x * 4 + (threadIdx.x >> 6);
  const float* kr = keys + (size_t)row * K_SZ;
  float a = kr[lane], c = kr[lane + 64];
  float s = a * a + c * c;
#pragma unroll
  for (int off = 32; off > 0; off >>= 1) s += __shfl_down(s, off);
  if (lane == 0) rnk[row] = 1.0f / fmaxf(sqrtf(s), 1e-8f);
}

// ---------------------------------------------------------------------------
// Kernel 3: fp32 sims + streaming partial top-3.
// Thread owns one batch row (query in 128 VGPRs); keys broadcast from LDS.
// grid (NC, B/256); each block covers 256 b x 2048 keys.
// ---------------------------------------------------------------------------
__global__ __launch_bounds__(256, 2)
void mann_sims(const float* __restrict__ qnT, const float* __restrict__ keys,
               const float* __restrict__ rnk, float* __restrict__ cval,
               int* __restrict__ cidx) {
  __shared__ float s_keys[KT][K_SZ + 4];   // pad: row stride 132 floats (16B-aligned)
  __shared__ float s_rnk[KT];
  const int t = threadIdx.x;
  const int b = blockIdx.y * 256 + t;
  const int m0 = blockIdx.x * MCHUNK;

  float4 qv[32];
#pragma unroll
  for (int i = 0; i < 32; ++i) {
    qv[i].x = qnT[(size_t)(4 * i + 0) * B_SZ + b];
    qv[i].y = qnT[(size_t)(4 * i + 1) * B_SZ + b];
    qv[i].z = qnT[(size_t)(4 * i + 2) * B_SZ + b];
    qv[i].w = qnT[(size_t)(4 * i + 3) * B_SZ + b];
  }

  float tv0 = NEG_INF, tv1 = NEG_INF, tv2 = NEG_INF;
  int ti0 = 0, ti1 = 0, ti2 = 0;

  for (int tile = 0; tile < MCHUNK / KT; ++tile) {
    const int mb = m0 + tile * KT;
    __syncthreads();
#pragma unroll
    for (int i = 0; i < 8; ++i) {
      int idx = i * 256 + t;                 // float4 slot 0..2047
      int r = idx >> 5, c = (idx & 31) << 2;
      float4 v = *(const float4*)(keys + (size_t)(mb + r) * K_SZ + c);
      *(float4*)&s_keys[r][c] = v;
    }
    if (t < KT) s_rnk[t] = rnk[mb + t];
    __syncthreads();

    for (int k = 0; k < KT; k += 4) {
      float a0 = 0.f, a1 = 0.f, a2 = 0.f, a3 = 0.f;
#pragma unroll
      for (int i = 0; i < 32; ++i) {
        float4 k0 = *(const float4*)&s_keys[k + 0][4 * i];
        float4 k1 = *(const float4*)&s_keys[k + 1][4 * i];
        float4 k2 = *(const float4*)&s_keys[k + 2][4 * i];
        float4 k3 = *(const float4*)&s_keys[k + 3][4 * i];
        a0 += qv[i].x * k0.x + qv[i].y * k0.y + qv[i].z * k0.z + qv[i].w * k0.w;
        a1 += qv[i].x * k1.x + qv[i].y * k1.y + qv[i].z * k1.z + qv[i].w * k1.w;
        a2 += qv[i].x * k2.x + qv[i].y * k2.y + qv[i].z * k2.z + qv[i].w * k2.w;
        a3 += qv[i].x * k3.x + qv[i].y * k3.y + qv[i].z * k3.z + qv[i].w * k3.w;
      }
      float v0 = a0 * s_rnk[k + 0];
      float v1 = a1 * s_rnk[k + 1];
      float v2 = a2 * s_rnk[k + 2];
      float v3 = a3 * s_rnk[k + 3];
      TOP3_INS(v0, mb + k + 0);
      TOP3_INS(v1, mb + k + 1);
      TOP3_INS(v2, mb + k + 2);
      TOP3_INS(v3, mb + k + 3);
    }
  }

  size_t base = ((size_t)b * NC + blockIdx.x) * 3;
  cval[base + 0] = tv0; cval[base + 1] = tv1; cval[base + 2] = tv2;
  cidx[base + 0] = ti0; cidx[base + 1] = ti1; cidx[base + 2] = ti2;
}

// ---------------------------------------------------------------------------
// Kernel 4: merge NC partial top-3 sets per batch row; one wave per row
// ---------------------------------------------------------------------------
__global__ void mann_merge(const float* __restrict__ cval,
                           const int* __restrict__ cidx,
                           float* __restrict__ tval, int* __restrict__ tidx) {
  const int lane = threadIdx.x & 63;
  const int b = blockIdx.x * 4 + (threadIdx.x >> 6);
  float tv0 = NEG_INF, tv1 = NEG_INF, tv2 = NEG_INF;
  int ti0 = 0, ti1 = 0, ti2 = 0;
  const int n = NC * 3;  // 192
  for (int i = lane; i < n; i += 64) {
    float v = cval[(size_t)b * n + i];
    int m = cidx[(size_t)b * n + i];
    TOP3_INS(v, m);
  }
#pragma unroll
  for (int off = 32; off > 0; off >>= 1) {
    float ov0 = __shfl_xor(tv0, off); int oi0 = __shfl_xor(ti0, off);
    float ov1 = __shfl_xor(tv1, off); int oi1 = __shfl_xor(ti1, off);
    float ov2 = __shfl_xor(tv2, off); int oi2 = __shfl_xor(ti2, off);
    TOP3_INS(ov0, oi0);
    TOP3_INS(ov1, oi1);
    TOP3_INS(ov2, oi2);
  }
  if (lane == 0) {
    tval[b * 3 + 0] = tv0; tval[b * 3 + 1] = tv1; tval[b * 3 + 2] = tv2;
    tidx[b * 3 + 0] = ti0; tidx[b * 3 + 1] = ti1; tidx[b * 3 + 2] = ti2;
  }
}

// ---------------------------------------------------------------------------
// Kernel 5: gather values, attention MLP + softmax, mem_vec, integration or
// fallback MLP. 8 batch rows per 256-thread block (block-uniform loop).
// ---------------------------------------------------------------------------
__global__ void mann_attn(const float* __restrict__ state,
                          const float* __restrict__ values,
                          const float* __restrict__ tval,
                          const int* __restrict__ tidx,
                          const float* __restrict__ a_w1, const float* __restrict__ a_b1,
                          const float* __restrict__ a_w2, const float* __restrict__ a_b2,
                          const float* __restrict__ i_w1, const float* __restrict__ i_b1,
                          const float* __restrict__ i_w2, const float* __restrict__ i_b2,
                          const float* __restrict__ f_w1, const float* __restrict__ f_b1,
                          const float* __restrict__ f_w2, const float* __restrict__ f_b2,
                          float* __restrict__ out) {
  __shared__ float s_state[256];
  __shared__ float s_v[3][256];
  __shared__ float s_h1[3][128];
  __shared__ float s_logit[3];
  __shared__ float s_attn[3];
  __shared__ float s_mem[256];
  __shared__ float s_h2[512];
  __shared__ float s_tv[3];
  __shared__ int s_idx[3];
  __shared__ int s_anyhit;

  const int t = threadIdx.x;

  for (int r = 0; r < 8; ++r) {
    const int b = blockIdx.x * 8 + r;
    __syncthreads();  // protect LDS reuse across r iterations

    s_state[t] = state[(size_t)b * E_SZ + t];
    if (t < 3) {
      s_idx[t] = tidx[b * 3 + t];
      s_tv[t] = tval[b * 3 + t];
    }
    __syncthreads();
#pragma unroll
    for (int k = 0; k < 3; ++k)
      s_v[k][t] = values[(size_t)s_idx[k] * V_SZ + t];
    __syncthreads();

    // attention hidden: h1[k][j] = tanh(b + state.A[:256,j] + v_k.A[256:,j])
    if (t < 128) {
      float sA = a_b1[t];
      for (int i = 0; i < 256; ++i) sA += s_state[i] * a_w1[i * 128 + t];
#pragma unroll
      for (int k = 0; k < 3; ++k) {
        float ak = sA;
        for (int i = 0; i < 256; ++i) ak += s_v[k][i] * a_w1[(256 + i) * 128 + t];
        s_h1[k][t] = tanhf(ak);
      }
    }
    __syncthreads();

    // logits via wave-0 reduction
    if (t < 64) {
#pragma unroll
      for (int k = 0; k < 3; ++k) {
        float p = s_h1[k][t] * a_w2[t] + s_h1[k][t + 64] * a_w2[t + 64];
#pragma unroll
        for (int off = 32; off > 0; off >>= 1) p += __shfl_down(p, off);
        if (t == 0) s_logit[k] = p + a_b2[0];
      }
    }
    __syncthreads();

    if (t == 0) {
      bool h0 = s_tv[0] >= 0.0f, h1 = s_tv[1] >= 0.0f, h2 = s_tv[2] >= 0.0f;
      float l0 = h0 ? s_logit[0] : -1e9f;
      float l1 = h1 ? s_logit[1] : -1e9f;
      float l2 = h2 ? s_logit[2] : -1e9f;
      float mx = fmaxf(l0, fmaxf(l1, l2));
      float e0 = expf(l0 - mx), e1 = expf(l1 - mx), e2 = expf(l2 - mx);
      float inv = 1.0f / (e0 + e1 + e2);
      s_attn[0] = e0 * inv; s_attn[1] = e1 * inv; s_attn[2] = e2 * inv;
      s_anyhit = (h0 || h1 || h2) ? 1 : 0;
    }
    __syncthreads();

    s_mem[t] = s_attn[0] * s_v[0][t] + s_attn[1] * s_v[1][t] + s_attn[2] * s_v[2][t];
    __syncthreads();

    if (s_anyhit) {
#pragma unroll
      for (int jj = 0; jj < 2; ++jj) {
        int j = t + jj * 256;
        float a = i_b1[j];
        for (int i = 0; i < 256; ++i) a += s_state[i] * i_w1[i * 512 + j];
        for (int i = 0; i < 256; ++i) a += s_mem[i] * i_w1[(256 + i) * 512 + j];
        s_h2[j] = fmaxf(a, 0.f);
      }
      __syncthreads();
      float o = i_b2[t];
      for (int i = 0; i < 512; ++i) o += s_h2[i] * i_w2[i * 256 + t];
      out[(size_t)b * O_SZ + t] = o;
    } else {
#pragma unroll
      for (int jj = 0; jj < 2; ++jj) {
        int j = t + jj * 256;
        float a = f_b1[j];
        for (int i = 0; i < 256; ++i) a += s_state[i] * f_w1[i * 512 + j];
        s_h2[j] = fmaxf(a, 0.f);
      }
      __syncthreads();
      float o = f_b2[t];
      for (int i = 0; i < 512; ++i) o += s_h2[i] * f_w2[i * 256 + t];
      out[(size_t)b * O_SZ + t] = o;
    }
  }
}

// ---------------------------------------------------------------------------
extern "C" void kernel_launch(void* const* d_in, const int* in_sizes, int n_in,
                              void* d_out, int out_size, void* d_ws, size_t ws_size,
                              hipStream_t stream) {
  const float* state = (const float*)d_in[0];
  const float* keys  = (const float*)d_in[1];
  const float* values = (const float*)d_in[2];
  const float* k_w1 = (const float*)d_in[3];
  const float* k_b1 = (const float*)d_in[4];
  const float* k_w2 = (const float*)d_in[5];
  const float* k_b2 = (const float*)d_in[6];
  const float* a_w1 = (const float*)d_in[7];
  const float* a_b1 = (const float*)d_in[8];
  const float* a_w2 = (const float*)d_in[9];
  const float* a_b2 = (const float*)d_in[10];
  const float* i_w1 = (const float*)d_in[11];
  const float* i_b1 = (const float*)d_in[12];
  const float* i_w2 = (const float*)d_in[13];
  const float* i_b2 = (const float*)d_in[14];
  const float* f_w1 = (const float*)d_in[15];
  const float* f_b1 = (const float*)d_in[16];
  const float* f_w2 = (const float*)d_in[17];
  const float* f_b2 = (const float*)d_in[18];
  float* out = (float*)d_out;

  float* ws = (float*)d_ws;
  float* qnT = ws + WS_QNT;
  float* rnk = ws + WS_RNK;
  float* cval = ws + WS_CVAL;
  int* cidx = (int*)(ws + WS_CIDX);
  float* tvalp = ws + WS_TVAL;
  int* tidxp = (int*)(ws + WS_TIDX);

  mann_encoder<<<B_SZ / 8, 256, 0, stream>>>(state, k_w1, k_b1, k_w2, k_b2, qnT);
  mann_keynorm<<<M_SZ / 4, 256, 0, stream>>>(keys, rnk);
  mann_sims<<<dim3(NC, B_SZ / 256), 256, 0, stream>>>(qnT, keys, rnk, cval, cidx);
  mann_merge<<<B_SZ / 4, 256, 0, stream>>>(cval, cidx, tvalp, tidxp);
  mann_attn<<<B_SZ / 8, 256, 0, stream>>>(state, values, tvalp, tidxp,
                                          a_w1, a_b1, a_w2, a_b2,
                                          i_w1, i_b1, i_w2, i_b2,
                                          f_w1, f_b1, f_w2, f_b2, out);
}

// Round 2
// 996.647 us; speedup vs baseline: 25.0050x; 25.0050x over previous
//
#include <hip/hip_runtime.h>
#include <math.h>

#define B_SZ 2048
#define M_SZ 131072
#define E_SZ 256
#define K_SZ 128
#define V_SZ 256
#define O_SZ 256

#define NCH  32                  // key chunks
#define CH   (M_SZ / NCH)        // 4096 keys per chunk
#define BT   128                 // batch rows per block
#define STG  64                  // keys per LDS stage
#define NSTG (CH / STG)          // 64 stages

// workspace layout (in float units)
#define WS_QN    0                              // fp32 qn [B][K]
#define WS_QNB   (WS_QN + B_SZ * K_SZ)          // bf16 qn [B][K] (ushort)
#define WS_KNB   (WS_QNB + B_SZ * K_SZ / 2)     // bf16 kn [M][K] (ushort)
#define WS_RNK   (WS_KNB + M_SZ * K_SZ / 2)     // fp32 1/||k|| [M]
#define WS_CAND  (WS_RNK + M_SZ)                // uint cand [B][NCH][16][3]
#define WS_TVAL  (WS_CAND + B_SZ * NCH * 16 * 3)
#define WS_TIDX  (WS_TVAL + B_SZ * 3)

#define NEG_INF (-3.0e38f)

typedef __attribute__((ext_vector_type(8))) short short8;
typedef __attribute__((ext_vector_type(4))) float f32x4;

static __device__ __forceinline__ unsigned short f2bf(float x) {
  unsigned u = __float_as_uint(x);
  unsigned r = (u + 0x7FFFu + ((u >> 16) & 1u)) >> 16;
  return (unsigned short)r;
}
// monotone bf16-bit transform for integer compare
static __device__ __forceinline__ unsigned flipbf(unsigned short h) {
  return (h & 0x8000u) ? (unsigned)(h ^ 0xFFFFu) : (unsigned)(h | 0x8000u);
}

static __device__ __forceinline__ void ins3f(float (&tv)[3], int (&ti)[3], float v, int m) {
  if (v > tv[2]) {
    if (v > tv[1]) {
      if (v > tv[0]) {
        tv[2] = tv[1]; ti[2] = ti[1]; tv[1] = tv[0]; ti[1] = ti[0]; tv[0] = v; ti[0] = m;
      } else {
        tv[2] = tv[1]; ti[2] = ti[1]; tv[1] = v; ti[1] = m;
      }
    } else {
      tv[2] = v; ti[2] = m;
    }
  }
}
static __device__ __forceinline__ void ins3u(unsigned (&tv)[3], int (&ti)[3], unsigned v, int m) {
  if (v > tv[2]) {
    if (v > tv[1]) {
      if (v > tv[0]) {
        tv[2] = tv[1]; ti[2] = ti[1]; tv[1] = tv[0]; ti[1] = ti[0]; tv[0] = v; ti[0] = m;
      } else {
        tv[2] = tv[1]; ti[2] = ti[1]; tv[1] = v; ti[1] = m;
      }
    } else {
      tv[2] = v; ti[2] = m;
    }
  }
}

// ---------------------------------------------------------------------------
// Kernel 1: key encoder -> normalized query (fp32 row-major + bf16 row-major)
// ---------------------------------------------------------------------------
__global__ void mann_encoder(const float* __restrict__ state,
                             const float* __restrict__ k_w1,
                             const float* __restrict__ k_b1,
                             const float* __restrict__ k_w2,
                             const float* __restrict__ k_b2,
                             float* __restrict__ qn,
                             unsigned short* __restrict__ qnb) {
  __shared__ float s_s[8][256];
  __shared__ float s_h[8][512];
  __shared__ float s_q[8][128];
  __shared__ float s_rn[8];
  const int t = threadIdx.x;
  const int b0 = blockIdx.x * 8;

#pragma unroll
  for (int i = 0; i < 8; ++i) {
    int idx = i * 256 + t;
    s_s[idx >> 8][idx & 255] = state[(size_t)b0 * E_SZ + idx];
  }
  __syncthreads();

  float acc0[8], acc1[8];
  {
    float ba = k_b1[t], bb = k_b1[t + 256];
#pragma unroll
    for (int r = 0; r < 8; ++r) { acc0[r] = ba; acc1[r] = bb; }
  }
  for (int i = 0; i < 256; ++i) {
    float w0 = k_w1[i * 512 + t];
    float w1 = k_w1[i * 512 + t + 256];
#pragma unroll
    for (int r = 0; r < 8; ++r) {
      acc0[r] += s_s[r][i] * w0;
      acc1[r] += s_s[r][i] * w1;
    }
  }
#pragma unroll
  for (int r = 0; r < 8; ++r) {
    s_h[r][t] = fmaxf(acc0[r], 0.f);
    s_h[r][t + 256] = fmaxf(acc1[r], 0.f);
  }
  __syncthreads();

  if (t < 128) {
    float a[8];
    float b2 = k_b2[t];
#pragma unroll
    for (int r = 0; r < 8; ++r) a[r] = b2;
    for (int i = 0; i < 512; ++i) {
      float w = k_w2[i * 128 + t];
#pragma unroll
      for (int r = 0; r < 8; ++r) a[r] += s_h[r][i] * w;
    }
#pragma unroll
    for (int r = 0; r < 8; ++r) s_q[r][t] = a[r];
  }
  __syncthreads();

  if (t < 8) {
    float s = 0.f;
    for (int j = 0; j < 128; ++j) { float v = s_q[t][j]; s += v * v; }
    s_rn[t] = 1.0f / fmaxf(sqrtf(s), 1e-8f);
  }
  __syncthreads();

  if (t < 128) {
#pragma unroll
    for (int r = 0; r < 8; ++r) {
      float q = s_q[r][t] * s_rn[r];
      qn[(size_t)(b0 + r) * K_SZ + t] = q;
      qnb[(size_t)(b0 + r) * K_SZ + t] = f2bf(q);
    }
  }
}

// ---------------------------------------------------------------------------
// Kernel 2: normalized bf16 keys + reciprocal norms. One wave per key row.
// ---------------------------------------------------------------------------
__global__ void mann_keyprep(const float* __restrict__ keys,
                             unsigned short* __restrict__ knb,
                             float* __restrict__ rnk) {
  const int lane = threadIdx.x & 63;
  const int row = blockIdx.x * 4 + (threadIdx.x >> 6);
  const float* kr = keys + (size_t)row * K_SZ;
  float a = kr[lane], c = kr[lane + 64];
  float s = a * a + c * c;
#pragma unroll
  for (int off = 32; off > 0; off >>= 1) s += __shfl_down(s, off);
  float rn = 1.0f / fmaxf(sqrtf(__shfl(s, 0)), 1e-8f);
  if (lane == 0) rnk[row] = rn;
  knb[(size_t)row * K_SZ + lane] = f2bf(a * rn);
  knb[(size_t)row * K_SZ + 64 + lane] = f2bf(c * rn);
}

// ---------------------------------------------------------------------------
// Kernel 3: bf16 MFMA sims + streaming per-thread top-3 candidates.
// grid (NCH, B/BT); block 256 = 4 waves; wave handles 32 batch rows.
// ---------------------------------------------------------------------------
__global__ __launch_bounds__(256)
void mann_sims_mfma(const unsigned short* __restrict__ qnb,
                    const unsigned short* __restrict__ knb,
                    unsigned* __restrict__ cand) {
  __shared__ unsigned short s_k[2][STG][136];  // +8 ushort pad -> 272 B row stride
  const int t = threadIdx.x;
  const int w = t >> 6, l = t & 63;
  const int lo = l & 15, g = l >> 4;
  const int chunk = blockIdx.x, bt = blockIdx.y;
  const int b0 = bt * BT + w * 32;
  const int k0 = chunk * CH;

  // A fragments: 2 rowtiles x 4 ksteps, held in registers for the whole kernel
  short8 afrag[2][4];
#pragma unroll
  for (int rti = 0; rti < 2; ++rti)
#pragma unroll
    for (int ks = 0; ks < 4; ++ks)
      afrag[rti][ks] = *(const short8*)(qnb + (size_t)(b0 + rti * 16 + lo) * K_SZ + ks * 32 + g * 8);

  float tv[2][4][3];
  int ti[2][4][3];
#pragma unroll
  for (int a = 0; a < 2; ++a)
#pragma unroll
    for (int b = 0; b < 4; ++b)
#pragma unroll
      for (int c = 0; c < 3; ++c) { tv[a][b][c] = NEG_INF; ti[a][b][c] = 0; }
  float thr[2] = {NEG_INF, NEG_INF};

  // staging: 4 float4 (=16 ushort) slots per thread per stage
  const int srow0 = t >> 4;        // slot rows for c = t, t+256, ... : row = c>>4
  const int scol = t & 15;         // 16B chunk within row
  float4 P[4];
#pragma unroll
  for (int i = 0; i < 4; ++i)
    P[i] = *(const float4*)(knb + (size_t)(k0 + srow0 + i * 16) * K_SZ + scol * 8);

  for (int s = 0; s < NSTG; ++s) {
    const int buf = s & 1;
#pragma unroll
    for (int i = 0; i < 4; ++i)
      *(float4*)&s_k[buf][srow0 + i * 16][scol * 8] = P[i];
    if (s + 1 < NSTG) {
#pragma unroll
      for (int i = 0; i < 4; ++i)
        P[i] = *(const float4*)(knb + (size_t)(k0 + (s + 1) * STG + srow0 + i * 16) * K_SZ + scol * 8);
    }
    __syncthreads();

#pragma unroll
    for (int kt = 0; kt < 4; ++kt) {
      short8 bfrag[4];
#pragma unroll
      for (int ks = 0; ks < 4; ++ks)
        bfrag[ks] = *(const short8*)&s_k[buf][kt * 16 + lo][ks * 32 + g * 8];
      const int kidx = s * STG + kt * 16 + lo;  // key index within chunk (col)
#pragma unroll
      for (int rti = 0; rti < 2; ++rti) {
        f32x4 c = {0.f, 0.f, 0.f, 0.f};
#pragma unroll
        for (int ks = 0; ks < 4; ++ks)
          c = __builtin_amdgcn_mfma_f32_16x16x32_bf16(afrag[rti][ks], bfrag[ks], c, 0, 0, 0);
        float mx = fmaxf(fmaxf(c[0], c[1]), fmaxf(c[2], c[3]));
        if (mx > thr[rti]) {
          ins3f(tv[rti][0], ti[rti][0], c[0], kidx);
          ins3f(tv[rti][1], ti[rti][1], c[1], kidx);
          ins3f(tv[rti][2], ti[rti][2], c[2], kidx);
          ins3f(tv[rti][3], ti[rti][3], c[3], kidx);
          thr[rti] = fminf(fminf(tv[rti][0][2], tv[rti][1][2]),
                           fminf(tv[rti][2][2], tv[rti][3][2]));
        }
      }
    }
    __syncthreads();
  }

  // emit candidates: cand[b][chunk][ct=lo][slot], packed (flip(bf16(v))<<16)|lidx
#pragma unroll
  for (int rti = 0; rti < 2; ++rti) {
#pragma unroll
    for (int j = 0; j < 4; ++j) {
      int b = b0 + rti * 16 + g * 4 + j;
      size_t base = (((size_t)b * NCH + chunk) * 16 + lo) * 3;
#pragma unroll
      for (int slot = 0; slot < 3; ++slot) {
        unsigned p = (flipbf(f2bf(tv[rti][j][slot])) << 16) | (unsigned)(ti[rti][j][slot] & 0xFFF);
        cand[base + slot] = p;
      }
    }
  }
}

// ---------------------------------------------------------------------------
// Kernel 4: merge candidates -> approx top-8 -> exact fp32 rescore -> top-3.
// One wave per batch row; block = 4 waves.
// ---------------------------------------------------------------------------
__global__ void mann_merge_rescore(const unsigned* __restrict__ cand,
                                   const float* __restrict__ qn,
                                   const float* __restrict__ keys,
                                   const float* __restrict__ rnk,
                                   float* __restrict__ tval,
                                   int* __restrict__ tidx) {
  __shared__ unsigned s_pv[4][192];
  __shared__ int s_gi[4][192];
  __shared__ float s_ex[4][8];
  const int t = threadIdx.x;
  const int w = t >> 6, l = t & 63;
  const int b = blockIdx.x * 4 + w;
  const int NCAND = NCH * 16 * 3;  // 1536 = 24 * 64

  unsigned pv[3] = {0u, 0u, 0u};
  int gi[3] = {0, 0, 0};
  for (int k = 0; k < NCAND / 64; ++k) {
    int i = l + k * 64;
    unsigned p = cand[(size_t)b * NCAND + i];
    int gidx = (i / 48) * CH + (int)(p & 0xFFFu);
    ins3u(pv, gi, p, gidx);
  }
#pragma unroll
  for (int j = 0; j < 3; ++j) { s_pv[w][l * 3 + j] = pv[j]; s_gi[w][l * 3 + j] = gi[j]; }
  __syncthreads();

  if (l == 0) {
    unsigned bv[8]; int bg[8];
#pragma unroll
    for (int j = 0; j < 8; ++j) { bv[j] = 0u; bg[j] = 0; }
    for (int i = 0; i < 192; ++i) {
      unsigned p = s_pv[w][i];
      if (p > bv[7]) {
        int gg = s_gi[w][i];
        int j = 7;
        while (j > 0 && p > bv[j - 1]) { bv[j] = bv[j - 1]; bg[j] = bg[j - 1]; --j; }
        bv[j] = p; bg[j] = gg;
      }
    }
#pragma unroll
    for (int j = 0; j < 8; ++j) s_gi[w][j] = bg[j];
  }
  __syncthreads();

  // exact fp32 rescore of the 8 candidates
  float q0 = qn[(size_t)b * K_SZ + l];
  float q1 = qn[(size_t)b * K_SZ + 64 + l];
#pragma unroll
  for (int d = 0; d < 8; ++d) {
    int idx = s_gi[w][d];
    float p = q0 * keys[(size_t)idx * K_SZ + l] + q1 * keys[(size_t)idx * K_SZ + 64 + l];
#pragma unroll
    for (int off = 32; off > 0; off >>= 1) p += __shfl_down(p, off);
    if (l == 0) s_ex[w][d] = p * rnk[idx];
  }
  __syncthreads();

  if (l == 0) {
    unsigned used = 0;
#pragma unroll
    for (int r = 0; r < 3; ++r) {
      float best = NEG_INF; int bd = 0;
      for (int d = 0; d < 8; ++d)
        if (!(used & (1u << d)) && s_ex[w][d] > best) { best = s_ex[w][d]; bd = d; }
      used |= (1u << bd);
      tval[b * 3 + r] = best;
      tidx[b * 3 + r] = s_gi[w][bd];
    }
  }
}

// ---------------------------------------------------------------------------
// Kernel 5: gather values, attention MLP + softmax, mem_vec, integration or
// fallback MLP. 8 batch rows per 256-thread block.
// ---------------------------------------------------------------------------
__global__ void mann_attn(const float* __restrict__ state,
                          const float* __restrict__ values,
                          const float* __restrict__ tval,
                          const int* __restrict__ tidx,
                          const float* __restrict__ a_w1, const float* __restrict__ a_b1,
                          const float* __restrict__ a_w2, const float* __restrict__ a_b2,
                          const float* __restrict__ i_w1, const float* __restrict__ i_b1,
                          const float* __restrict__ i_w2, const float* __restrict__ i_b2,
                          const float* __restrict__ f_w1, const float* __restrict__ f_b1,
                          const float* __restrict__ f_w2, const float* __restrict__ f_b2,
                          float* __restrict__ out) {
  __shared__ float s_state[256];
  __shared__ float s_v[3][256];
  __shared__ float s_h1[3][128];
  __shared__ float s_logit[3];
  __shared__ float s_attn[3];
  __shared__ float s_mem[256];
  __shared__ float s_h2[512];
  __shared__ float s_tv[3];
  __shared__ int s_idx[3];
  __shared__ int s_anyhit;

  const int t = threadIdx.x;

  for (int r = 0; r < 8; ++r) {
    const int b = blockIdx.x * 8 + r;
    __syncthreads();

    s_state[t] = state[(size_t)b * E_SZ + t];
    if (t < 3) {
      s_idx[t] = tidx[b * 3 + t];
      s_tv[t] = tval[b * 3 + t];
    }
    __syncthreads();
#pragma unroll
    for (int k = 0; k < 3; ++k)
      s_v[k][t] = values[(size_t)s_idx[k] * V_SZ + t];
    __syncthreads();

    if (t < 128) {
      float sA = a_b1[t];
      for (int i = 0; i < 256; ++i) sA += s_state[i] * a_w1[i * 128 + t];
#pragma unroll
      for (int k = 0; k < 3; ++k) {
        float ak = sA;
        for (int i = 0; i < 256; ++i) ak += s_v[k][i] * a_w1[(256 + i) * 128 + t];
        s_h1[k][t] = tanhf(ak);
      }
    }
    __syncthreads();

    if (t < 64) {
#pragma unroll
      for (int k = 0; k < 3; ++k) {
        float p = s_h1[k][t] * a_w2[t] + s_h1[k][t + 64] * a_w2[t + 64];
#pragma unroll
        for (int off = 32; off > 0; off >>= 1) p += __shfl_down(p, off);
        if (t == 0) s_logit[k] = p + a_b2[0];
      }
    }
    __syncthreads();

    if (t == 0) {
      bool h0 = s_tv[0] >= 0.0f, h1 = s_tv[1] >= 0.0f, h2 = s_tv[2] >= 0.0f;
      float l0 = h0 ? s_logit[0] : -1e9f;
      float l1 = h1 ? s_logit[1] : -1e9f;
      float l2 = h2 ? s_logit[2] : -1e9f;
      float mx = fmaxf(l0, fmaxf(l1, l2));
      float e0 = expf(l0 - mx), e1 = expf(l1 - mx), e2 = expf(l2 - mx);
      float inv = 1.0f / (e0 + e1 + e2);
      s_attn[0] = e0 * inv; s_attn[1] = e1 * inv; s_attn[2] = e2 * inv;
      s_anyhit = (h0 || h1 || h2) ? 1 : 0;
    }
    __syncthreads();

    s_mem[t] = s_attn[0] * s_v[0][t] + s_attn[1] * s_v[1][t] + s_attn[2] * s_v[2][t];
    __syncthreads();

    if (s_anyhit) {
#pragma unroll
      for (int jj = 0; jj < 2; ++jj) {
        int j = t + jj * 256;
        float a = i_b1[j];
        for (int i = 0; i < 256; ++i) a += s_state[i] * i_w1[i * 512 + j];
        for (int i = 0; i < 256; ++i) a += s_mem[i] * i_w1[(256 + i) * 512 + j];
        s_h2[j] = fmaxf(a, 0.f);
      }
      __syncthreads();
      float o = i_b2[t];
      for (int i = 0; i < 512; ++i) o += s_h2[i] * i_w2[i * 256 + t];
      out[(size_t)b * O_SZ + t] = o;
    } else {
#pragma unroll
      for (int jj = 0; jj < 2; ++jj) {
        int j = t + jj * 256;
        float a = f_b1[j];
        for (int i = 0; i < 256; ++i) a += s_state[i] * f_w1[i * 512 + j];
        s_h2[j] = fmaxf(a, 0.f);
      }
      __syncthreads();
      float o = f_b2[t];
      for (int i = 0; i < 512; ++i) o += s_h2[i] * f_w2[i * 256 + t];
      out[(size_t)b * O_SZ + t] = o;
    }
  }
}

// ---------------------------------------------------------------------------
extern "C" void kernel_launch(void* const* d_in, const int* in_sizes, int n_in,
                              void* d_out, int out_size, void* d_ws, size_t ws_size,
                              hipStream_t stream) {
  const float* state = (const float*)d_in[0];
  const float* keys  = (const float*)d_in[1];
  const float* values = (const float*)d_in[2];
  const float* k_w1 = (const float*)d_in[3];
  const float* k_b1 = (const float*)d_in[4];
  const float* k_w2 = (const float*)d_in[5];
  const float* k_b2 = (const float*)d_in[6];
  const float* a_w1 = (const float*)d_in[7];
  const float* a_b1 = (const float*)d_in[8];
  const float* a_w2 = (const float*)d_in[9];
  const float* a_b2 = (const float*)d_in[10];
  const float* i_w1 = (const float*)d_in[11];
  const float* i_b1 = (const float*)d_in[12];
  const float* i_w2 = (const float*)d_in[13];
  const float* i_b2 = (const float*)d_in[14];
  const float* f_w1 = (const float*)d_in[15];
  const float* f_b1 = (const float*)d_in[16];
  const float* f_w2 = (const float*)d_in[17];
  const float* f_b2 = (const float*)d_in[18];
  float* out = (float*)d_out;

  float* ws = (float*)d_ws;
  float* qn = ws + WS_QN;
  unsigned short* qnb = (unsigned short*)(ws + WS_QNB);
  unsigned short* knb = (unsigned short*)(ws + WS_KNB);
  float* rnk = ws + WS_RNK;
  unsigned* cand = (unsigned*)(ws + WS_CAND);
  float* tvalp = ws + WS_TVAL;
  int* tidxp = (int*)(ws + WS_TIDX);

  mann_encoder<<<B_SZ / 8, 256, 0, stream>>>(state, k_w1, k_b1, k_w2, k_b2, qn, qnb);
  mann_keyprep<<<M_SZ / 4, 256, 0, stream>>>(keys, knb, rnk);
  mann_sims_mfma<<<dim3(NCH, B_SZ / BT), 256, 0, stream>>>(qnb, knb, cand);
  mann_merge_rescore<<<B_SZ / 4, 256, 0, stream>>>(cand, qn, keys, rnk, tvalp, tidxp);
  mann_attn<<<B_SZ / 8, 256, 0, stream>>>(state, values, tvalp, tidxp,
                                          a_w1, a_b1, a_w2, a_b2,
                                          i_w1, i_b1, i_w2, i_b2,
                                          f_w1, f_b1, f_w2, f_b2, out);
}

// Round 3
// 800.702 us; speedup vs baseline: 31.1241x; 1.2447x over previous
//
#include <hip/hip_runtime.h>
#include <math.h>

#define B_SZ 2048
#define M_SZ 131072
#define E_SZ 256
#define K_SZ 128
#define V_SZ 256
#define O_SZ 256

#define NCH  32                  // key chunks
#define CH   (M_SZ / NCH)        // 4096 keys per chunk
#define BT   128                 // batch rows per block
#define STG  64                  // keys per LDS stage
#define NSTG (CH / STG)          // 64 stages

// workspace layout (in float units)
#define WS_QN    0                              // fp32 qn [B][K]
#define WS_QNB   (WS_QN + B_SZ * K_SZ)          // bf16 qn [B][K] (ushort)
#define WS_KNB   (WS_QNB + B_SZ * K_SZ / 2)     // bf16 kn [M][K] (ushort)
#define WS_RNK   (WS_KNB + M_SZ * K_SZ / 2)     // fp32 1/||k|| [M]
#define WS_CAND  (WS_RNK + M_SZ)                // uint cand [B][NCH][16][3]
#define WS_TVAL  (WS_CAND + B_SZ * NCH * 16 * 3)
#define WS_TIDX  (WS_TVAL + B_SZ * 3)

#define NEG_INF (-3.0e38f)

typedef __attribute__((ext_vector_type(8))) short short8;
typedef __attribute__((ext_vector_type(4))) float f32x4;

static __device__ __forceinline__ unsigned short f2bf(float x) {
  unsigned u = __float_as_uint(x);
  unsigned r = (u + 0x7FFFu + ((u >> 16) & 1u)) >> 16;
  return (unsigned short)r;
}
// monotone bf16-bit transform for integer compare
static __device__ __forceinline__ unsigned flipbf(unsigned short h) {
  return (h & 0x8000u) ? (unsigned)(h ^ 0xFFFFu) : (unsigned)(h | 0x8000u);
}

static __device__ __forceinline__ void ins3f(float (&tv)[3], int (&ti)[3], float v, int m) {
  if (v > tv[2]) {
    if (v > tv[1]) {
      if (v > tv[0]) {
        tv[2] = tv[1]; ti[2] = ti[1]; tv[1] = tv[0]; ti[1] = ti[0]; tv[0] = v; ti[0] = m;
      } else {
        tv[2] = tv[1]; ti[2] = ti[1]; tv[1] = v; ti[1] = m;
      }
    } else {
      tv[2] = v; ti[2] = m;
    }
  }
}
static __device__ __forceinline__ void ins3u(unsigned (&tv)[3], int (&ti)[3], unsigned v, int m) {
  if (v > tv[2]) {
    if (v > tv[1]) {
      if (v > tv[0]) {
        tv[2] = tv[1]; ti[2] = ti[1]; tv[1] = tv[0]; ti[1] = ti[0]; tv[0] = v; ti[0] = m;
      } else {
        tv[2] = tv[1]; ti[2] = ti[1]; tv[1] = v; ti[1] = m;
      }
    } else {
      tv[2] = v; ti[2] = m;
    }
  }
}

// ---------------------------------------------------------------------------
// Kernel 1: key encoder -> normalized query (fp32 row-major + bf16 row-major)
// ---------------------------------------------------------------------------
__global__ void mann_encoder(const float* __restrict__ state,
                             const float* __restrict__ k_w1,
                             const float* __restrict__ k_b1,
                             const float* __restrict__ k_w2,
                             const float* __restrict__ k_b2,
                             float* __restrict__ qn,
                             unsigned short* __restrict__ qnb) {
  __shared__ float s_s[8][256];
  __shared__ float s_h[8][512];
  __shared__ float s_q[8][128];
  __shared__ float s_rn[8];
  const int t = threadIdx.x;
  const int b0 = blockIdx.x * 8;

#pragma unroll
  for (int i = 0; i < 8; ++i) {
    int idx = i * 256 + t;
    s_s[idx >> 8][idx & 255] = state[(size_t)b0 * E_SZ + idx];
  }
  __syncthreads();

  float acc0[8], acc1[8];
  {
    float ba = k_b1[t], bb = k_b1[t + 256];
#pragma unroll
    for (int r = 0; r < 8; ++r) { acc0[r] = ba; acc1[r] = bb; }
  }
  for (int i = 0; i < 256; ++i) {
    float w0 = k_w1[i * 512 + t];
    float w1 = k_w1[i * 512 + t + 256];
#pragma unroll
    for (int r = 0; r < 8; ++r) {
      acc0[r] += s_s[r][i] * w0;
      acc1[r] += s_s[r][i] * w1;
    }
  }
#pragma unroll
  for (int r = 0; r < 8; ++r) {
    s_h[r][t] = fmaxf(acc0[r], 0.f);
    s_h[r][t + 256] = fmaxf(acc1[r], 0.f);
  }
  __syncthreads();

  if (t < 128) {
    float a[8];
    float b2 = k_b2[t];
#pragma unroll
    for (int r = 0; r < 8; ++r) a[r] = b2;
    for (int i = 0; i < 512; ++i) {
      float w = k_w2[i * 128 + t];
#pragma unroll
      for (int r = 0; r < 8; ++r) a[r] += s_h[r][i] * w;
    }
#pragma unroll
    for (int r = 0; r < 8; ++r) s_q[r][t] = a[r];
  }
  __syncthreads();

  if (t < 8) {
    float s = 0.f;
    for (int j = 0; j < 128; ++j) { float v = s_q[t][j]; s += v * v; }
    s_rn[t] = 1.0f / fmaxf(sqrtf(s), 1e-8f);
  }
  __syncthreads();

  if (t < 128) {
#pragma unroll
    for (int r = 0; r < 8; ++r) {
      float q = s_q[r][t] * s_rn[r];
      qn[(size_t)(b0 + r) * K_SZ + t] = q;
      qnb[(size_t)(b0 + r) * K_SZ + t] = f2bf(q);
    }
  }
}

// ---------------------------------------------------------------------------
// Kernel 2: normalized bf16 keys + reciprocal norms. One wave per key row.
// ---------------------------------------------------------------------------
__global__ void mann_keyprep(const float* __restrict__ keys,
                             unsigned short* __restrict__ knb,
                             float* __restrict__ rnk) {
  const int lane = threadIdx.x & 63;
  const int row = blockIdx.x * 4 + (threadIdx.x >> 6);
  const float* kr = keys + (size_t)row * K_SZ;
  float a = kr[lane], c = kr[lane + 64];
  float s = a * a + c * c;
#pragma unroll
  for (int off = 32; off > 0; off >>= 1) s += __shfl_down(s, off);
  float rn = 1.0f / fmaxf(sqrtf(__shfl(s, 0)), 1e-8f);
  if (lane == 0) rnk[row] = rn;
  knb[(size_t)row * K_SZ + lane] = f2bf(a * rn);
  knb[(size_t)row * K_SZ + 64 + lane] = f2bf(c * rn);
}

// ---------------------------------------------------------------------------
// Kernel 3: bf16 MFMA sims + streaming per-thread top-3 candidates.
// grid (NCH, B/BT); block 256 = 4 waves; wave handles 32 batch rows.
// ---------------------------------------------------------------------------
__global__ __launch_bounds__(256)
void mann_sims_mfma(const unsigned short* __restrict__ qnb,
                    const unsigned short* __restrict__ knb,
                    unsigned* __restrict__ cand) {
  __shared__ unsigned short s_k[2][STG][136];  // +8 ushort pad -> 272 B row stride
  const int t = threadIdx.x;
  const int w = t >> 6, l = t & 63;
  const int lo = l & 15, g = l >> 4;
  const int chunk = blockIdx.x, bt = blockIdx.y;
  const int b0 = bt * BT + w * 32;
  const int k0 = chunk * CH;

  // A fragments: 2 rowtiles x 4 ksteps, held in registers for the whole kernel
  short8 afrag[2][4];
#pragma unroll
  for (int rti = 0; rti < 2; ++rti)
#pragma unroll
    for (int ks = 0; ks < 4; ++ks)
      afrag[rti][ks] = *(const short8*)(qnb + (size_t)(b0 + rti * 16 + lo) * K_SZ + ks * 32 + g * 8);

  float tv[2][4][3];
  int ti[2][4][3];
#pragma unroll
  for (int a = 0; a < 2; ++a)
#pragma unroll
    for (int b = 0; b < 4; ++b)
#pragma unroll
      for (int c = 0; c < 3; ++c) { tv[a][b][c] = NEG_INF; ti[a][b][c] = 0; }
  float thr[2] = {NEG_INF, NEG_INF};

  // staging: 4 float4 (=16 ushort) slots per thread per stage
  const int srow0 = t >> 4;        // slot rows for c = t, t+256, ... : row = c>>4
  const int scol = t & 15;         // 16B chunk within row
  float4 P[4];
#pragma unroll
  for (int i = 0; i < 4; ++i)
    P[i] = *(const float4*)(knb + (size_t)(k0 + srow0 + i * 16) * K_SZ + scol * 8);

  for (int s = 0; s < NSTG; ++s) {
    const int buf = s & 1;
#pragma unroll
    for (int i = 0; i < 4; ++i)
      *(float4*)&s_k[buf][srow0 + i * 16][scol * 8] = P[i];
    if (s + 1 < NSTG) {
#pragma unroll
      for (int i = 0; i < 4; ++i)
        P[i] = *(const float4*)(knb + (size_t)(k0 + (s + 1) * STG + srow0 + i * 16) * K_SZ + scol * 8);
    }
    __syncthreads();

#pragma unroll
    for (int kt = 0; kt < 4; ++kt) {
      short8 bfrag[4];
#pragma unroll
      for (int ks = 0; ks < 4; ++ks)
        bfrag[ks] = *(const short8*)&s_k[buf][kt * 16 + lo][ks * 32 + g * 8];
      const int kidx = s * STG + kt * 16 + lo;  // key index within chunk (col)
#pragma unroll
      for (int rti = 0; rti < 2; ++rti) {
        f32x4 c = {0.f, 0.f, 0.f, 0.f};
#pragma unroll
        for (int ks = 0; ks < 4; ++ks)
          c = __builtin_amdgcn_mfma_f32_16x16x32_bf16(afrag[rti][ks], bfrag[ks], c, 0, 0, 0);
        float mx = fmaxf(fmaxf(c[0], c[1]), fmaxf(c[2], c[3]));
        if (mx > thr[rti]) {
          ins3f(tv[rti][0], ti[rti][0], c[0], kidx);
          ins3f(tv[rti][1], ti[rti][1], c[1], kidx);
          ins3f(tv[rti][2], ti[rti][2], c[2], kidx);
          ins3f(tv[rti][3], ti[rti][3], c[3], kidx);
          thr[rti] = fminf(fminf(tv[rti][0][2], tv[rti][1][2]),
                           fminf(tv[rti][2][2], tv[rti][3][2]));
        }
      }
    }
    __syncthreads();
  }

  // emit candidates: cand[b][chunk][ct=lo][slot], packed (flip(bf16(v))<<16)|lidx
#pragma unroll
  for (int rti = 0; rti < 2; ++rti) {
#pragma unroll
    for (int j = 0; j < 4; ++j) {
      int b = b0 + rti * 16 + g * 4 + j;
      size_t base = (((size_t)b * NCH + chunk) * 16 + lo) * 3;
#pragma unroll
      for (int slot = 0; slot < 3; ++slot) {
        unsigned p = (flipbf(f2bf(tv[rti][j][slot])) << 16) | (unsigned)(ti[rti][j][slot] & 0xFFF);
        cand[base + slot] = p;
      }
    }
  }
}

// ---------------------------------------------------------------------------
// Kernel 4: merge candidates -> approx top-8 -> exact fp32 rescore -> top-3.
// One wave per batch row; block = 4 waves.
// ---------------------------------------------------------------------------
__global__ void mann_merge_rescore(const unsigned* __restrict__ cand,
                                   const float* __restrict__ qn,
                                   const float* __restrict__ keys,
                                   const float* __restrict__ rnk,
                                   float* __restrict__ tval,
                                   int* __restrict__ tidx) {
  __shared__ unsigned s_pv[4][192];
  __shared__ int s_gi[4][192];
  __shared__ float s_ex[4][8];
  const int t = threadIdx.x;
  const int w = t >> 6, l = t & 63;
  const int b = blockIdx.x * 4 + w;
  const int NCAND = NCH * 16 * 3;  // 1536 = 24 * 64

  unsigned pv[3] = {0u, 0u, 0u};
  int gi[3] = {0, 0, 0};
  for (int k = 0; k < NCAND / 64; ++k) {
    int i = l + k * 64;
    unsigned p = cand[(size_t)b * NCAND + i];
    int gidx = (i / 48) * CH + (int)(p & 0xFFFu);
    ins3u(pv, gi, p, gidx);
  }
#pragma unroll
  for (int j = 0; j < 3; ++j) { s_pv[w][l * 3 + j] = pv[j]; s_gi[w][l * 3 + j] = gi[j]; }
  __syncthreads();

  if (l == 0) {
    unsigned bv[8]; int bg[8];
#pragma unroll
    for (int j = 0; j < 8; ++j) { bv[j] = 0u; bg[j] = 0; }
    for (int i = 0; i < 192; ++i) {
      unsigned p = s_pv[w][i];
      if (p > bv[7]) {
        int gg = s_gi[w][i];
        int j = 7;
        while (j > 0 && p > bv[j - 1]) { bv[j] = bv[j - 1]; bg[j] = bg[j - 1]; --j; }
        bv[j] = p; bg[j] = gg;
      }
    }
#pragma unroll
    for (int j = 0; j < 8; ++j) s_gi[w][j] = bg[j];
  }
  __syncthreads();

  // exact fp32 rescore of the 8 candidates
  float q0 = qn[(size_t)b * K_SZ + l];
  float q1 = qn[(size_t)b * K_SZ + 64 + l];
#pragma unroll
  for (int d = 0; d < 8; ++d) {
    int idx = s_gi[w][d];
    float p = q0 * keys[(size_t)idx * K_SZ + l] + q1 * keys[(size_t)idx * K_SZ + 64 + l];
#pragma unroll
    for (int off = 32; off > 0; off >>= 1) p += __shfl_down(p, off);
    if (l == 0) s_ex[w][d] = p * rnk[idx];
  }
  __syncthreads();

  if (l == 0) {
    unsigned used = 0;
#pragma unroll
    for (int r = 0; r < 3; ++r) {
      float best = NEG_INF; int bd = 0;
      for (int d = 0; d < 8; ++d)
        if (!(used & (1u << d)) && s_ex[w][d] > best) { best = s_ex[w][d]; bd = d; }
      used |= (1u << bd);
      tval[b * 3 + r] = best;
      tidx[b * 3 + r] = s_gi[w][bd];
    }
  }
}

// ---------------------------------------------------------------------------
// Kernel 5: fused tail — attention MLP + softmax + mem_vec + integration (or
// fallback). 8 batch rows per 256-thread block, all rows in parallel,
// register-blocked so every weight load feeds 8-16 FMAs.
// ---------------------------------------------------------------------------
__global__ __launch_bounds__(256)
void mann_tail(const float* __restrict__ state,
               const float* __restrict__ values,
               const float* __restrict__ tval,
               const int* __restrict__ tidx,
               const float* __restrict__ a_w1, const float* __restrict__ a_b1,
               const float* __restrict__ a_w2, const float* __restrict__ a_b2,
               const float* __restrict__ i_w1, const float* __restrict__ i_b1,
               const float* __restrict__ i_w2, const float* __restrict__ i_b2,
               const float* __restrict__ f_w1, const float* __restrict__ f_b1,
               const float* __restrict__ f_w2, const float* __restrict__ f_b2,
               float* __restrict__ out) {
  __shared__ float s_state[8][256];   // 8 KB
  __shared__ float s_v[24][256];      // 24 KB   p = r*3+k
  __shared__ float s_h1[24][132];     // 12.7 KB (pad 4 -> spread banks)
  __shared__ float s_mem[8][256];     // 8 KB
  __shared__ float s_h2[8][512];      // 16 KB
  __shared__ float s_logit[24];
  __shared__ float s_attn[8][3];
  __shared__ int s_idx[24];
  __shared__ float s_tvl[24];
  __shared__ int s_hit[8];

  const int t = threadIdx.x;
  const int b0 = blockIdx.x * 8;

  // ---- load state rows + top-3 metadata ----
#pragma unroll
  for (int r = 0; r < 8; ++r)
    s_state[r][t] = state[(size_t)(b0 + r) * E_SZ + t];
  if (t < 24) {
    s_idx[t] = tidx[b0 * 3 + t];
    s_tvl[t] = tval[b0 * 3 + t];
  }
  __syncthreads();

  // ---- gather retrieved values (24 rows, coalesced) ----
#pragma unroll
  for (int p = 0; p < 24; ++p)
    s_v[p][t] = values[(size_t)s_idx[p] * V_SZ + t];
  __syncthreads();

  // ---- attention hidden h1[p][j] = tanh(b + state.A + v.A) ----
  {
    const int j = t & 127;
    const int half = t >> 7;              // rows r = half*4 .. half*4+3
    float racc[4];
    {
      float bias = a_b1[j];
#pragma unroll
      for (int rr = 0; rr < 4; ++rr) racc[rr] = bias;
    }
    for (int i = 0; i < 256; ++i) {
      float wv = a_w1[i * 128 + j];
#pragma unroll
      for (int rr = 0; rr < 4; ++rr)
        racc[rr] += s_state[half * 4 + rr][i] * wv;
    }
    float pacc[12];
#pragma unroll
    for (int q = 0; q < 12; ++q) pacc[q] = racc[q / 3];
    for (int i = 0; i < 256; ++i) {
      float wv = a_w1[(256 + i) * 128 + j];
#pragma unroll
      for (int q = 0; q < 12; ++q)
        pacc[q] += s_v[half * 12 + q][i] * wv;
    }
#pragma unroll
    for (int q = 0; q < 12; ++q)
      s_h1[half * 12 + q][j] = tanhf(pacc[q]);
  }
  __syncthreads();

  // ---- logits: 24 dot-128 with a_w2, 8 threads each ----
  if (t < 192) {
    const int p = t >> 3, l8 = t & 7;
    float acc = 0.f;
    for (int i = l8; i < 128; i += 8)
      acc += s_h1[p][i] * a_w2[i];
#pragma unroll
    for (int off = 4; off > 0; off >>= 1) acc += __shfl_down(acc, off, 8);
    if (l8 == 0) s_logit[p] = acc + a_b2[0];
  }
  __syncthreads();

  // ---- softmax + hit mask (one thread per row) ----
  if (t < 8) {
    bool h0 = s_tvl[t * 3 + 0] >= 0.0f;
    bool h1 = s_tvl[t * 3 + 1] >= 0.0f;
    bool h2 = s_tvl[t * 3 + 2] >= 0.0f;
    float l0 = h0 ? s_logit[t * 3 + 0] : -1e9f;
    float l1 = h1 ? s_logit[t * 3 + 1] : -1e9f;
    float l2 = h2 ? s_logit[t * 3 + 2] : -1e9f;
    float mx = fmaxf(l0, fmaxf(l1, l2));
    float e0 = expf(l0 - mx), e1 = expf(l1 - mx), e2 = expf(l2 - mx);
    float inv = 1.0f / (e0 + e1 + e2);
    s_attn[t][0] = e0 * inv; s_attn[t][1] = e1 * inv; s_attn[t][2] = e2 * inv;
    s_hit[t] = (h0 || h1 || h2) ? 1 : 0;
  }
  __syncthreads();

  // ---- mem_vec ----
#pragma unroll
  for (int r = 0; r < 8; ++r)
    s_mem[r][t] = s_attn[r][0] * s_v[r * 3 + 0][t] +
                  s_attn[r][1] * s_v[r * 3 + 1][t] +
                  s_attn[r][2] * s_v[r * 3 + 2][t];
  __syncthreads();

  // ---- integration hidden: h2[r][t], h2[r][t+256] for all 8 rows ----
  {
    float acc0[8], acc1[8];
    {
      float ba = i_b1[t], bb = i_b1[t + 256];
#pragma unroll
      for (int r = 0; r < 8; ++r) { acc0[r] = ba; acc1[r] = bb; }
    }
    for (int i = 0; i < 256; ++i) {
      float w0 = i_w1[i * 512 + t];
      float w1 = i_w1[i * 512 + t + 256];
#pragma unroll
      for (int r = 0; r < 8; ++r) {
        acc0[r] += s_state[r][i] * w0;
        acc1[r] += s_state[r][i] * w1;
      }
    }
    for (int i = 0; i < 256; ++i) {
      float w0 = i_w1[(256 + i) * 512 + t];
      float w1 = i_w1[(256 + i) * 512 + t + 256];
#pragma unroll
      for (int r = 0; r < 8; ++r) {
        acc0[r] += s_mem[r][i] * w0;
        acc1[r] += s_mem[r][i] * w1;
      }
    }
#pragma unroll
    for (int r = 0; r < 8; ++r) {
      s_h2[r][t] = fmaxf(acc0[r], 0.f);
      s_h2[r][t + 256] = fmaxf(acc1[r], 0.f);
    }
  }
  __syncthreads();

  // ---- integration output ----
  {
    float acc[8];
    {
      float bb = i_b2[t];
#pragma unroll
      for (int r = 0; r < 8; ++r) acc[r] = bb;
    }
    for (int i = 0; i < 512; ++i) {
      float wv = i_w2[i * 256 + t];
#pragma unroll
      for (int r = 0; r < 8; ++r) acc[r] += s_h2[r][i] * wv;
    }
#pragma unroll
    for (int r = 0; r < 8; ++r)
      out[(size_t)(b0 + r) * O_SZ + t] = acc[r];
  }

  // ---- fallback fix-up for miss rows (block-uniform branch; ~never taken) ----
  for (int r = 0; r < 8; ++r) {
    if (!s_hit[r]) {
      __syncthreads();
      float a0 = f_b1[t], a1 = f_b1[t + 256];
      for (int i = 0; i < 256; ++i) {
        float x = s_state[r][i];
        a0 += x * f_w1[i * 512 + t];
        a1 += x * f_w1[i * 512 + t + 256];
      }
      s_h2[r][t] = fmaxf(a0, 0.f);
      s_h2[r][t + 256] = fmaxf(a1, 0.f);
      __syncthreads();
      float o = f_b2[t];
      for (int i = 0; i < 512; ++i) o += s_h2[r][i] * f_w2[i * 256 + t];
      out[(size_t)(b0 + r) * O_SZ + t] = o;
    }
  }
}

// ---------------------------------------------------------------------------
extern "C" void kernel_launch(void* const* d_in, const int* in_sizes, int n_in,
                              void* d_out, int out_size, void* d_ws, size_t ws_size,
                              hipStream_t stream) {
  const float* state = (const float*)d_in[0];
  const float* keys  = (const float*)d_in[1];
  const float* values = (const float*)d_in[2];
  const float* k_w1 = (const float*)d_in[3];
  const float* k_b1 = (const float*)d_in[4];
  const float* k_w2 = (const float*)d_in[5];
  const float* k_b2 = (const float*)d_in[6];
  const float* a_w1 = (const float*)d_in[7];
  const float* a_b1 = (const float*)d_in[8];
  const float* a_w2 = (const float*)d_in[9];
  const float* a_b2 = (const float*)d_in[10];
  const float* i_w1 = (const float*)d_in[11];
  const float* i_b1 = (const float*)d_in[12];
  const float* i_w2 = (const float*)d_in[13];
  const float* i_b2 = (const float*)d_in[14];
  const float* f_w1 = (const float*)d_in[15];
  const float* f_b1 = (const float*)d_in[16];
  const float* f_w2 = (const float*)d_in[17];
  const float* f_b2 = (const float*)d_in[18];
  float* out = (float*)d_out;

  float* ws = (float*)d_ws;
  float* qn = ws + WS_QN;
  unsigned short* qnb = (unsigned short*)(ws + WS_QNB);
  unsigned short* knb = (unsigned short*)(ws + WS_KNB);
  float* rnk = ws + WS_RNK;
  unsigned* cand = (unsigned*)(ws + WS_CAND);
  float* tvalp = ws + WS_TVAL;
  int* tidxp = (int*)(ws + WS_TIDX);

  mann_encoder<<<B_SZ / 8, 256, 0, stream>>>(state, k_w1, k_b1, k_w2, k_b2, qn, qnb);
  mann_keyprep<<<M_SZ / 4, 256, 0, stream>>>(keys, knb, rnk);
  mann_sims_mfma<<<dim3(NCH, B_SZ / BT), 256, 0, stream>>>(qnb, knb, cand);
  mann_merge_rescore<<<B_SZ / 4, 256, 0, stream>>>(cand, qn, keys, rnk, tvalp, tidxp);
  mann_tail<<<B_SZ / 8, 256, 0, stream>>>(state, values, tvalp, tidxp,
                                          a_w1, a_b1, a_w2, a_b2,
                                          i_w1, i_b1, i_w2, i_b2,
                                          f_w1, f_b1, f_w2, f_b2, out);
}

// Round 4
// 792.505 us; speedup vs baseline: 31.4460x; 1.0103x over previous
//
#include <hip/hip_runtime.h>
#include <math.h>

#define B_SZ 2048
#define M_SZ 131072
#define E_SZ 256
#define K_SZ 128
#define V_SZ 256
#define O_SZ 256

#define NCH  32                  // key chunks
#define CH   (M_SZ / NCH)        // 4096 keys per chunk
#define BT   128                 // batch rows per block
#define STG  64                  // keys per LDS stage
#define NSTG (CH / STG)          // 64 stages

// workspace layout (in float units)
#define WS_QN    0                              // fp32 qn [B][K]
#define WS_QNB   (WS_QN + B_SZ * K_SZ)          // bf16 qn [B][K] (ushort)
#define WS_KNB   (WS_QNB + B_SZ * K_SZ / 2)     // bf16 kn [M][K] (ushort, SWIZZLED)
#define WS_RNK   (WS_KNB + M_SZ * K_SZ / 2)     // fp32 1/||k|| [M]
#define WS_CAND  (WS_RNK + M_SZ)                // uint cand [B][NCH][16][3]
#define WS_TVAL  (WS_CAND + B_SZ * NCH * 16 * 3)
#define WS_TIDX  (WS_TVAL + B_SZ * 3)

#define NEG_INF (-3.0e38f)

typedef __attribute__((ext_vector_type(8))) short short8;
typedef __attribute__((ext_vector_type(4))) float f32x4;

// broadcast lane jj's value of x to all lanes via v_readlane (SGPR result)
#define RDL(x, jj) __int_as_float(__builtin_amdgcn_readlane(__float_as_int(x), (jj)))

static __device__ __forceinline__ void gl_lds16(const void* gptr, void* ldsptr) {
  __builtin_amdgcn_global_load_lds(
      (const __attribute__((address_space(1))) unsigned int*)gptr,
      (__attribute__((address_space(3))) unsigned int*)ldsptr, 16, 0, 0);
}

static __device__ __forceinline__ unsigned short f2bf(float x) {
  unsigned u = __float_as_uint(x);
  unsigned r = (u + 0x7FFFu + ((u >> 16) & 1u)) >> 16;
  return (unsigned short)r;
}
// monotone bf16-bit transform for integer compare
static __device__ __forceinline__ unsigned flipbf(unsigned short h) {
  return (h & 0x8000u) ? (unsigned)(h ^ 0xFFFFu) : (unsigned)(h | 0x8000u);
}

static __device__ __forceinline__ void ins3f(float (&tv)[3], int (&ti)[3], float v, int m) {
  if (v > tv[2]) {
    if (v > tv[1]) {
      if (v > tv[0]) {
        tv[2] = tv[1]; ti[2] = ti[1]; tv[1] = tv[0]; ti[1] = ti[0]; tv[0] = v; ti[0] = m;
      } else {
        tv[2] = tv[1]; ti[2] = ti[1]; tv[1] = v; ti[1] = m;
      }
    } else {
      tv[2] = v; ti[2] = m;
    }
  }
}
static __device__ __forceinline__ void ins3u(unsigned (&tv)[3], int (&ti)[3], unsigned v, int m) {
  if (v > tv[2]) {
    if (v > tv[1]) {
      if (v > tv[0]) {
        tv[2] = tv[1]; ti[2] = ti[1]; tv[1] = tv[0]; ti[1] = ti[0]; tv[0] = v; ti[0] = m;
      } else {
        tv[2] = tv[1]; ti[2] = ti[1]; tv[1] = v; ti[1] = m;
      }
    } else {
      tv[2] = v; ti[2] = m;
    }
  }
}

// ---------------------------------------------------------------------------
// Kernel 1: key encoder -> normalized query (fp32 + bf16). readlane GEMMs.
// ---------------------------------------------------------------------------
__global__ __launch_bounds__(256)
void mann_encoder(const float* __restrict__ state,
                  const float* __restrict__ k_w1,
                  const float* __restrict__ k_b1,
                  const float* __restrict__ k_w2,
                  const float* __restrict__ k_b2,
                  float* __restrict__ qn,
                  unsigned short* __restrict__ qnb) {
  __shared__ float s_s[8][256];
  __shared__ float s_h[8][512];
  __shared__ float s_q[8][128];
  __shared__ float s_rn[8];
  const int t = threadIdx.x;
  const int l = t & 63;
  const int b0 = blockIdx.x * 8;

#pragma unroll
  for (int i = 0; i < 8; ++i) {
    int idx = i * 256 + t;
    s_s[idx >> 8][idx & 255] = state[(size_t)b0 * E_SZ + idx];
  }
  __syncthreads();

  // hidden: thread t -> cols t, t+256; x broadcast via readlane
  {
    float acc0[8], acc1[8];
    float ba = k_b1[t], bb = k_b1[t + 256];
#pragma unroll
    for (int r = 0; r < 8; ++r) { acc0[r] = ba; acc1[r] = bb; }
    for (int ib = 0; ib < 4; ++ib) {
      float xr[8];
#pragma unroll
      for (int r = 0; r < 8; ++r) xr[r] = s_s[r][ib * 64 + l];
#pragma unroll 4
      for (int jj = 0; jj < 64; ++jj) {
        int i = ib * 64 + jj;
        float w0 = k_w1[i * 512 + t];
        float w1 = k_w1[i * 512 + t + 256];
#pragma unroll
        for (int r = 0; r < 8; ++r) {
          float x = RDL(xr[r], jj);
          acc0[r] += x * w0;
          acc1[r] += x * w1;
        }
      }
    }
#pragma unroll
    for (int r = 0; r < 8; ++r) {
      s_h[r][t] = fmaxf(acc0[r], 0.f);
      s_h[r][t + 256] = fmaxf(acc1[r], 0.f);
    }
  }
  __syncthreads();

  // output layer: threads 0..127 -> q col t
  if (t < 128) {
    float a[8];
    float b2 = k_b2[t];
#pragma unroll
    for (int r = 0; r < 8; ++r) a[r] = b2;
    for (int ib = 0; ib < 8; ++ib) {
      float xr[8];
#pragma unroll
      for (int r = 0; r < 8; ++r) xr[r] = s_h[r][ib * 64 + l];
#pragma unroll 4
      for (int jj = 0; jj < 64; ++jj) {
        float w = k_w2[(ib * 64 + jj) * 128 + t];
#pragma unroll
        for (int r = 0; r < 8; ++r) a[r] += RDL(xr[r], jj) * w;
      }
    }
#pragma unroll
    for (int r = 0; r < 8; ++r) s_q[r][t] = a[r];
  }
  __syncthreads();

  if (t < 8) {
    float s = 0.f;
    for (int j = 0; j < 128; ++j) { float v = s_q[t][j]; s += v * v; }
    s_rn[t] = 1.0f / fmaxf(sqrtf(s), 1e-8f);
  }
  __syncthreads();

  if (t < 128) {
#pragma unroll
    for (int r = 0; r < 8; ++r) {
      float q = s_q[r][t] * s_rn[r];
      qn[(size_t)(b0 + r) * K_SZ + t] = q;
      qnb[(size_t)(b0 + r) * K_SZ + t] = f2bf(q);
    }
  }
}

// ---------------------------------------------------------------------------
// Kernel 2: normalized bf16 keys (PRE-SWIZZLED layout) + reciprocal norms.
// Chunk c (8 ushorts) of row r stored at position (c&8)|((c&7)^(r&7)).
// ---------------------------------------------------------------------------
__global__ void mann_keyprep(const float* __restrict__ keys,
                             unsigned short* __restrict__ knbsw,
                             float* __restrict__ rnk) {
  const int lane = threadIdx.x & 63;
  const int row = blockIdx.x * 4 + (threadIdx.x >> 6);
  const float* kr = keys + (size_t)row * K_SZ;
  float a = kr[lane], c = kr[lane + 64];
  float s = a * a + c * c;
#pragma unroll
  for (int off = 32; off > 0; off >>= 1) s += __shfl_down(s, off);
  float rn = 1.0f / fmaxf(sqrtf(__shfl(s, 0)), 1e-8f);
  if (lane == 0) rnk[row] = rn;
  const int r7 = row & 7;
  const int c1 = lane >> 3, j = lane & 7;
  unsigned short* base = knbsw + (size_t)row * 128;
  base[(c1 ^ r7) * 8 + j] = f2bf(a * rn);                 // chunks 0..7
  base[(8 | (c1 ^ r7)) * 8 + j] = f2bf(c * rn);           // chunks 8..15
}

// ---------------------------------------------------------------------------
// Kernel 3: bf16 MFMA sims + streaming per-thread top-3 candidates.
// Async global_load_lds staging into swizzled, unpadded, conflict-free LDS.
// grid (NCH, B/BT); block 256 = 4 waves; wave handles 32 batch rows.
// ---------------------------------------------------------------------------
__global__ __launch_bounds__(256, 2)
void mann_sims_mfma(const unsigned short* __restrict__ qnb,
                    const unsigned short* __restrict__ knbsw,
                    unsigned* __restrict__ cand) {
  __shared__ unsigned short s_k[2 * STG * 128];  // 32 KB, two 16 KB buffers
  const int t = threadIdx.x;
  const int w = t >> 6, l = t & 63;
  const int lo = l & 15, g = l >> 4;
  const int chunk = blockIdx.x, bt = blockIdx.y;
  const int b0 = bt * BT + w * 32;
  const int k0 = chunk * CH;

  // A fragments: 2 rowtiles x 4 ksteps, registers for whole kernel
  short8 afrag[2][4];
#pragma unroll
  for (int rti = 0; rti < 2; ++rti)
#pragma unroll
    for (int ks = 0; ks < 4; ++ks)
      afrag[rti][ks] = *(const short8*)(qnb + (size_t)(b0 + rti * 16 + lo) * K_SZ + ks * 32 + g * 8);

  float tv[2][4][3];
  int ti[2][4][3];
#pragma unroll
  for (int a = 0; a < 2; ++a)
#pragma unroll
    for (int b = 0; b < 4; ++b)
#pragma unroll
      for (int c = 0; c < 3; ++c) { tv[a][b][c] = NEG_INF; ti[a][b][c] = 0; }
  float thr[2] = {NEG_INF, NEG_INF};

  // per-lane swizzled ds_read base addrs (bytes): row lo, chunk (ks*4+g)
  const int ev = lo * 256 + ((g ^ (lo & 7)) << 4);   // ks even
  const int od = ev ^ 64;                            // ks odd (chunk^4)

  const char* gbase = (const char*)knbsw + (size_t)k0 * 256;
  char* lds0 = (char*)s_k;

  // issue one 16 KB stage: 4 x 1KB segments per wave (lane-linear copy)
#define ISSUE_STAGE(S, BUF)                                                  \
  do {                                                                       \
    const char* g0 = gbase + (size_t)(S) * 16384;                            \
    char* l0 = lds0 + (BUF) * 16384;                                         \
    _Pragma("unroll")                                                        \
    for (int i = 0; i < 4; ++i) {                                            \
      int seg = i * 4 + w;                                                   \
      gl_lds16(g0 + seg * 1024 + l * 16, l0 + seg * 1024);                   \
    }                                                                        \
  } while (0)

  ISSUE_STAGE(0, 0);

  for (int s = 0; s < NSTG; ++s) {
    const int buf = s & 1;
    __syncthreads();                       // drains vmcnt: stage s resident
    if (s + 1 < NSTG) ISSUE_STAGE(s + 1, buf ^ 1);   // overlaps with compute

    const int vev = ev + (buf << 14);
    const int vod = od + (buf << 14);
#pragma unroll
    for (int kt = 0; kt < 4; ++kt) {
      short8 bfrag[4];
#pragma unroll
      for (int ks = 0; ks < 4; ++ks) {
        int va = (ks & 1) ? vod : vev;
        bfrag[ks] = *(const short8*)((const char*)s_k + va + kt * 4096 + ((ks & 2) ? 128 : 0));
      }
      const int kidx = s * STG + kt * 16 + lo;  // key index within chunk
#pragma unroll
      for (int rti = 0; rti < 2; ++rti) {
        f32x4 c = {0.f, 0.f, 0.f, 0.f};
#pragma unroll
        for (int ks = 0; ks < 4; ++ks)
          c = __builtin_amdgcn_mfma_f32_16x16x32_bf16(afrag[rti][ks], bfrag[ks], c, 0, 0, 0);
        float mx = fmaxf(fmaxf(c[0], c[1]), fmaxf(c[2], c[3]));
        if (mx > thr[rti]) {
          ins3f(tv[rti][0], ti[rti][0], c[0], kidx);
          ins3f(tv[rti][1], ti[rti][1], c[1], kidx);
          ins3f(tv[rti][2], ti[rti][2], c[2], kidx);
          ins3f(tv[rti][3], ti[rti][3], c[3], kidx);
          thr[rti] = fminf(fminf(tv[rti][0][2], tv[rti][1][2]),
                           fminf(tv[rti][2][2], tv[rti][3][2]));
        }
      }
    }
  }
#undef ISSUE_STAGE

  // emit candidates: cand[b][chunk][ct=lo][slot], packed (flip(bf16(v))<<16)|lidx
#pragma unroll
  for (int rti = 0; rti < 2; ++rti) {
#pragma unroll
    for (int j = 0; j < 4; ++j) {
      int b = b0 + rti * 16 + g * 4 + j;
      size_t base = (((size_t)b * NCH + chunk) * 16 + lo) * 3;
#pragma unroll
      for (int slot = 0; slot < 3; ++slot) {
        unsigned p = (flipbf(f2bf(tv[rti][j][slot])) << 16) | (unsigned)(ti[rti][j][slot] & 0xFFF);
        cand[base + slot] = p;
      }
    }
  }
}

// ---------------------------------------------------------------------------
// Kernel 4: merge candidates -> approx top-8 -> exact fp32 rescore -> top-3.
// ---------------------------------------------------------------------------
__global__ void mann_merge_rescore(const unsigned* __restrict__ cand,
                                   const float* __restrict__ qn,
                                   const float* __restrict__ keys,
                                   const float* __restrict__ rnk,
                                   float* __restrict__ tval,
                                   int* __restrict__ tidx) {
  __shared__ unsigned s_pv[4][192];
  __shared__ int s_gi[4][192];
  __shared__ float s_ex[4][8];
  const int t = threadIdx.x;
  const int w = t >> 6, l = t & 63;
  const int b = blockIdx.x * 4 + w;
  const int NCAND = NCH * 16 * 3;  // 1536 = 24 * 64

  unsigned pv[3] = {0u, 0u, 0u};
  int gi[3] = {0, 0, 0};
  for (int k = 0; k < NCAND / 64; ++k) {
    int i = l + k * 64;
    unsigned p = cand[(size_t)b * NCAND + i];
    int gidx = (i / 48) * CH + (int)(p & 0xFFFu);
    ins3u(pv, gi, p, gidx);
  }
#pragma unroll
  for (int j = 0; j < 3; ++j) { s_pv[w][l * 3 + j] = pv[j]; s_gi[w][l * 3 + j] = gi[j]; }
  __syncthreads();

  if (l == 0) {
    unsigned bv[8]; int bg[8];
#pragma unroll
    for (int j = 0; j < 8; ++j) { bv[j] = 0u; bg[j] = 0; }
    for (int i = 0; i < 192; ++i) {
      unsigned p = s_pv[w][i];
      if (p > bv[7]) {
        int gg = s_gi[w][i];
        int j = 7;
        while (j > 0 && p > bv[j - 1]) { bv[j] = bv[j - 1]; bg[j] = bg[j - 1]; --j; }
        bv[j] = p; bg[j] = gg;
      }
    }
#pragma unroll
    for (int j = 0; j < 8; ++j) s_gi[w][j] = bg[j];
  }
  __syncthreads();

  // exact fp32 rescore of the 8 candidates
  float q0 = qn[(size_t)b * K_SZ + l];
  float q1 = qn[(size_t)b * K_SZ + 64 + l];
#pragma unroll
  for (int d = 0; d < 8; ++d) {
    int idx = s_gi[w][d];
    float p = q0 * keys[(size_t)idx * K_SZ + l] + q1 * keys[(size_t)idx * K_SZ + 64 + l];
#pragma unroll
    for (int off = 32; off > 0; off >>= 1) p += __shfl_down(p, off);
    if (l == 0) s_ex[w][d] = p * rnk[idx];
  }
  __syncthreads();

  if (l == 0) {
    unsigned used = 0;
#pragma unroll
    for (int r = 0; r < 3; ++r) {
      float best = NEG_INF; int bd = 0;
      for (int d = 0; d < 8; ++d)
        if (!(used & (1u << d)) && s_ex[w][d] > best) { best = s_ex[w][d]; bd = d; }
      used |= (1u << bd);
      tval[b * 3 + r] = best;
      tidx[b * 3 + r] = s_gi[w][bd];
    }
  }
}

// ---------------------------------------------------------------------------
// Kernel 5: fused tail, readlane-blocked GEMM phases (fp32-exact).
// 8 batch rows per 256-thread block.
// ---------------------------------------------------------------------------
__global__ __launch_bounds__(256)
void mann_tail(const float* __restrict__ state,
               const float* __restrict__ values,
               const float* __restrict__ tval,
               const int* __restrict__ tidx,
               const float* __restrict__ a_w1, const float* __restrict__ a_b1,
               const float* __restrict__ a_w2, const float* __restrict__ a_b2,
               const float* __restrict__ i_w1, const float* __restrict__ i_b1,
               const float* __restrict__ i_w2, const float* __restrict__ i_b2,
               const float* __restrict__ f_w1, const float* __restrict__ f_b1,
               const float* __restrict__ f_w2, const float* __restrict__ f_b2,
               float* __restrict__ out) {
  __shared__ float s_state[8][256];
  __shared__ float s_v[24][256];
  __shared__ float s_h1[24][132];
  __shared__ float s_mem[8][256];
  __shared__ float s_h2[8][512];
  __shared__ float s_logit[24];
  __shared__ float s_attn[8][3];
  __shared__ int s_idx[24];
  __shared__ float s_tvl[24];
  __shared__ int s_hit[8];

  const int t = threadIdx.x;
  const int l = t & 63;
  const int b0 = blockIdx.x * 8;

#pragma unroll
  for (int r = 0; r < 8; ++r)
    s_state[r][t] = state[(size_t)(b0 + r) * E_SZ + t];
  if (t < 24) {
    s_idx[t] = tidx[b0 * 3 + t];
    s_tvl[t] = tval[b0 * 3 + t];
  }
  __syncthreads();

#pragma unroll
  for (int p = 0; p < 24; ++p)
    s_v[p][t] = values[(size_t)s_idx[p] * V_SZ + t];
  __syncthreads();

  // ---- attention hidden h1[p][j] ----
  {
    const int j = t & 127;
    const int half = t >> 7;              // rows half*4..+3, v-streams half*12..+11
    float racc[4];
    {
      float bias = a_b1[j];
#pragma unroll
      for (int rr = 0; rr < 4; ++rr) racc[rr] = bias;
    }
    for (int ib = 0; ib < 4; ++ib) {
      float xr[4];
#pragma unroll
      for (int rr = 0; rr < 4; ++rr) xr[rr] = s_state[half * 4 + rr][ib * 64 + l];
#pragma unroll 4
      for (int jj = 0; jj < 64; ++jj) {
        float wv = a_w1[(ib * 64 + jj) * 128 + j];
#pragma unroll
        for (int rr = 0; rr < 4; ++rr)
          racc[rr] += RDL(xr[rr], jj) * wv;
      }
    }
    float pacc[12];
#pragma unroll
    for (int q = 0; q < 12; ++q) pacc[q] = racc[q / 3];
    for (int ib = 0; ib < 4; ++ib) {
      float xv[12];
#pragma unroll
      for (int q = 0; q < 12; ++q) xv[q] = s_v[half * 12 + q][ib * 64 + l];
#pragma unroll 2
      for (int jj = 0; jj < 64; ++jj) {
        float wv = a_w1[(256 + ib * 64 + jj) * 128 + j];
#pragma unroll
        for (int q = 0; q < 12; ++q)
          pacc[q] += RDL(xv[q], jj) * wv;
      }
    }
#pragma unroll
    for (int q = 0; q < 12; ++q)
      s_h1[half * 12 + q][j] = tanhf(pacc[q]);
  }
  __syncthreads();

  // ---- logits ----
  if (t < 192) {
    const int p = t >> 3, l8 = t & 7;
    float acc = 0.f;
    for (int i = l8; i < 128; i += 8)
      acc += s_h1[p][i] * a_w2[i];
#pragma unroll
    for (int off = 4; off > 0; off >>= 1) acc += __shfl_down(acc, off, 8);
    if (l8 == 0) s_logit[p] = acc + a_b2[0];
  }
  __syncthreads();

  // ---- softmax + hit mask ----
  if (t < 8) {
    bool h0 = s_tvl[t * 3 + 0] >= 0.0f;
    bool h1 = s_tvl[t * 3 + 1] >= 0.0f;
    bool h2 = s_tvl[t * 3 + 2] >= 0.0f;
    float l0 = h0 ? s_logit[t * 3 + 0] : -1e9f;
    float l1 = h1 ? s_logit[t * 3 + 1] : -1e9f;
    float l2 = h2 ? s_logit[t * 3 + 2] : -1e9f;
    float mx = fmaxf(l0, fmaxf(l1, l2));
    float e0 = expf(l0 - mx), e1 = expf(l1 - mx), e2 = expf(l2 - mx);
    float inv = 1.0f / (e0 + e1 + e2);
    s_attn[t][0] = e0 * inv; s_attn[t][1] = e1 * inv; s_attn[t][2] = e2 * inv;
    s_hit[t] = (h0 || h1 || h2) ? 1 : 0;
  }
  __syncthreads();

  // ---- mem_vec ----
#pragma unroll
  for (int r = 0; r < 8; ++r)
    s_mem[r][t] = s_attn[r][0] * s_v[r * 3 + 0][t] +
                  s_attn[r][1] * s_v[r * 3 + 1][t] +
                  s_attn[r][2] * s_v[r * 3 + 2][t];
  __syncthreads();

  // ---- integration hidden ----
  {
    float acc0[8], acc1[8];
    {
      float ba = i_b1[t], bb = i_b1[t + 256];
#pragma unroll
      for (int r = 0; r < 8; ++r) { acc0[r] = ba; acc1[r] = bb; }
    }
    for (int ib = 0; ib < 4; ++ib) {
      float xr[8];
#pragma unroll
      for (int r = 0; r < 8; ++r) xr[r] = s_state[r][ib * 64 + l];
#pragma unroll 2
      for (int jj = 0; jj < 64; ++jj) {
        int i = ib * 64 + jj;
        float w0 = i_w1[i * 512 + t];
        float w1 = i_w1[i * 512 + t + 256];
#pragma unroll
        for (int r = 0; r < 8; ++r) {
          float x = RDL(xr[r], jj);
          acc0[r] += x * w0;
          acc1[r] += x * w1;
        }
      }
    }
    for (int ib = 0; ib < 4; ++ib) {
      float xr[8];
#pragma unroll
      for (int r = 0; r < 8; ++r) xr[r] = s_mem[r][ib * 64 + l];
#pragma unroll 2
      for (int jj = 0; jj < 64; ++jj) {
        int i = ib * 64 + jj;
        float w0 = i_w1[(256 + i) * 512 + t];
        float w1 = i_w1[(256 + i) * 512 + t + 256];
#pragma unroll
        for (int r = 0; r < 8; ++r) {
          float x = RDL(xr[r], jj);
          acc0[r] += x * w0;
          acc1[r] += x * w1;
        }
      }
    }
#pragma unroll
    for (int r = 0; r < 8; ++r) {
      s_h2[r][t] = fmaxf(acc0[r], 0.f);
      s_h2[r][t + 256] = fmaxf(acc1[r], 0.f);
    }
  }
  __syncthreads();

  // ---- integration output ----
  {
    float acc[8];
    {
      float bb = i_b2[t];
#pragma unroll
      for (int r = 0; r < 8; ++r) acc[r] = bb;
    }
    for (int ib = 0; ib < 8; ++ib) {
      float xr[8];
#pragma unroll
      for (int r = 0; r < 8; ++r) xr[r] = s_h2[r][ib * 64 + l];
#pragma unroll 4
      for (int jj = 0; jj < 64; ++jj) {
        float wv = i_w2[(ib * 64 + jj) * 256 + t];
#pragma unroll
        for (int r = 0; r < 8; ++r) acc[r] += RDL(xr[r], jj) * wv;
      }
    }
#pragma unroll
    for (int r = 0; r < 8; ++r)
      out[(size_t)(b0 + r) * O_SZ + t] = acc[r];
  }

  // ---- fallback fix-up for miss rows (block-uniform; ~never taken) ----
  for (int r = 0; r < 8; ++r) {
    if (!s_hit[r]) {
      __syncthreads();
      float a0 = f_b1[t], a1 = f_b1[t + 256];
      for (int i = 0; i < 256; ++i) {
        float x = s_state[r][i];
        a0 += x * f_w1[i * 512 + t];
        a1 += x * f_w1[i * 512 + t + 256];
      }
      s_h2[r][t] = fmaxf(a0, 0.f);
      s_h2[r][t + 256] = fmaxf(a1, 0.f);
      __syncthreads();
      float o = f_b2[t];
      for (int i = 0; i < 512; ++i) o += s_h2[r][i] * f_w2[i * 256 + t];
      out[(size_t)(b0 + r) * O_SZ + t] = o;
    }
  }
}

// ---------------------------------------------------------------------------
extern "C" void kernel_launch(void* const* d_in, const int* in_sizes, int n_in,
                              void* d_out, int out_size, void* d_ws, size_t ws_size,
                              hipStream_t stream) {
  const float* state = (const float*)d_in[0];
  const float* keys  = (const float*)d_in[1];
  const float* values = (const float*)d_in[2];
  const float* k_w1 = (const float*)d_in[3];
  const float* k_b1 = (const float*)d_in[4];
  const float* k_w2 = (const float*)d_in[5];
  const float* k_b2 = (const float*)d_in[6];
  const float* a_w1 = (const float*)d_in[7];
  const float* a_b1 = (const float*)d_in[8];
  const float* a_w2 = (const float*)d_in[9];
  const float* a_b2 = (const float*)d_in[10];
  const float* i_w1 = (const float*)d_in[11];
  const float* i_b1 = (const float*)d_in[12];
  const float* i_w2 = (const float*)d_in[13];
  const float* i_b2 = (const float*)d_in[14];
  const float* f_w1 = (const float*)d_in[15];
  const float* f_b1 = (const float*)d_in[16];
  const float* f_w2 = (const float*)d_in[17];
  const float* f_b2 = (const float*)d_in[18];
  float* out = (float*)d_out;

  float* ws = (float*)d_ws;
  float* qn = ws + WS_QN;
  unsigned short* qnb = (unsigned short*)(ws + WS_QNB);
  unsigned short* knbsw = (unsigned short*)(ws + WS_KNB);
  float* rnk = ws + WS_RNK;
  unsigned* cand = (unsigned*)(ws + WS_CAND);
  float* tvalp = ws + WS_TVAL;
  int* tidxp = (int*)(ws + WS_TIDX);

  mann_encoder<<<B_SZ / 8, 256, 0, stream>>>(state, k_w1, k_b1, k_w2, k_b2, qn, qnb);
  mann_keyprep<<<M_SZ / 4, 256, 0, stream>>>(keys, knbsw, rnk);
  mann_sims_mfma<<<dim3(NCH, B_SZ / BT), 256, 0, stream>>>(qnb, knbsw, cand);
  mann_merge_rescore<<<B_SZ / 4, 256, 0, stream>>>(cand, qn, keys, rnk, tvalp, tidxp);
  mann_tail<<<B_SZ / 8, 256, 0, stream>>>(state, values, tvalp, tidxp,
                                          a_w1, a_b1, a_w2, a_b2,
                                          i_w1, i_b1, i_w2, i_b2,
                                          f_w1, f_b1, f_w2, f_b2, out);
}

// Round 5
// 753.009 us; speedup vs baseline: 33.0954x; 1.0525x over previous
//
#include <hip/hip_runtime.h>
#include <math.h>

#define B_SZ 2048
#define M_SZ 131072
#define E_SZ 256
#define K_SZ 128
#define V_SZ 256
#define O_SZ 256

#define NCH  32                  // key chunks
#define CH   (M_SZ / NCH)        // 4096 keys per chunk
#define BT   128                 // batch rows per block
#define STG  64                  // keys per LDS stage
#define NSTG (CH / STG)          // 64 stages

// workspace layout (in float units)
#define WS_QN    0                              // fp32 qn [B][K]
#define WS_QNB   (WS_QN + B_SZ * K_SZ)          // bf16 qn [B][K] (ushort)
#define WS_KNB   (WS_QNB + B_SZ * K_SZ / 2)     // bf16 kn [M][K] (ushort, SWIZZLED)
#define WS_RNK   (WS_KNB + M_SZ * K_SZ / 2)     // fp32 1/||k|| [M]
#define WS_CAND  (WS_RNK + M_SZ)                // uint cand [B][NCH][16][3] (3.146M)
#define WS_TVAL  (WS_CAND + B_SZ * NCH * 16 * 3)
#define WS_TIDX  (WS_TVAL + B_SZ * 3)
// aliases inside the CAND region (disjoint lifetimes):
//   henc [B][512]  : enc1 -> enc2   (before sims writes cand)
//   mem  [B][256], h2 [B][512], hit [B] : T1 -> T2b (after merge reads cand)
#define WS_HENC  WS_CAND
#define WS_MEM   WS_CAND
#define WS_H2    (WS_CAND + B_SZ * V_SZ)
#define WS_HIT   (WS_H2 + B_SZ * 512)

#define NEG_INF (-3.0e38f)

typedef __attribute__((ext_vector_type(8))) short short8;
typedef __attribute__((ext_vector_type(4))) float f32x4;

static __device__ __forceinline__ void gl_lds16(const void* gptr, void* ldsptr) {
  __builtin_amdgcn_global_load_lds(
      (const __attribute__((address_space(1))) unsigned int*)gptr,
      (__attribute__((address_space(3))) unsigned int*)ldsptr, 16, 0, 0);
}

static __device__ __forceinline__ unsigned short f2bf(float x) {
  unsigned u = __float_as_uint(x);
  unsigned r = (u + 0x7FFFu + ((u >> 16) & 1u)) >> 16;
  return (unsigned short)r;
}
static __device__ __forceinline__ unsigned flipbf(unsigned short h) {
  return (h & 0x8000u) ? (unsigned)(h ^ 0xFFFFu) : (unsigned)(h | 0x8000u);
}

static __device__ __forceinline__ void ins3f(float (&tv)[3], int (&ti)[3], float v, int m) {
  if (v > tv[2]) {
    if (v > tv[1]) {
      if (v > tv[0]) {
        tv[2] = tv[1]; ti[2] = ti[1]; tv[1] = tv[0]; ti[1] = ti[0]; tv[0] = v; ti[0] = m;
      } else {
        tv[2] = tv[1]; ti[2] = ti[1]; tv[1] = v; ti[1] = m;
      }
    } else {
      tv[2] = v; ti[2] = m;
    }
  }
}
static __device__ __forceinline__ void ins3u(unsigned (&tv)[3], int (&ti)[3], unsigned v, int m) {
  if (v > tv[2]) {
    if (v > tv[1]) {
      if (v > tv[0]) {
        tv[2] = tv[1]; ti[2] = ti[1]; tv[1] = tv[0]; ti[1] = ti[0]; tv[0] = v; ti[0] = m;
      } else {
        tv[2] = tv[1]; ti[2] = ti[1]; tv[1] = v; ti[1] = m;
      }
    } else {
      tv[2] = v; ti[2] = m;
    }
  }
}

// ---------------------------------------------------------------------------
// enc1: henc = relu(state @ k_w1 + b1).  [B,512], K=256.
// grid (B/8, 2); 256 thr; thread owns 1 col of its 256-col slice, 8 rows.
// x via scalar loads (uniform addr), w via coalesced vector loads.
// ---------------------------------------------------------------------------
__global__ __launch_bounds__(256)
void mann_enc1(const float* __restrict__ state,
               const float* __restrict__ k_w1,
               const float* __restrict__ k_b1,
               float* __restrict__ henc) {
  const int t = threadIdx.x;
  const int c = blockIdx.y * 256 + t;
  const int b0 = blockIdx.x * 8;
  float acc[8];
  const float bias = k_b1[c];
#pragma unroll
  for (int r = 0; r < 8; ++r) acc[r] = bias;
#pragma unroll 4
  for (int k = 0; k < 256; ++k) {
    const float w = k_w1[k * 512 + c];
#pragma unroll
    for (int r = 0; r < 8; ++r)
      acc[r] += state[(size_t)(b0 + r) * E_SZ + k] * w;
  }
#pragma unroll
  for (int r = 0; r < 8; ++r)
    henc[(size_t)(b0 + r) * 512 + c] = fmaxf(acc[r], 0.f);
}

// ---------------------------------------------------------------------------
// enc2: q = henc @ k_w2 + b2, normalize -> qn (fp32) + qnb (bf16).
// grid (B/4); 128 thr; thread owns col j, 4 rows.
// ---------------------------------------------------------------------------
__global__ __launch_bounds__(128)
void mann_enc2(const float* __restrict__ henc,
               const float* __restrict__ k_w2,
               const float* __restrict__ k_b2,
               float* __restrict__ qn,
               unsigned short* __restrict__ qnb) {
  __shared__ float s_part[2][4];
  const int t = threadIdx.x;
  const int l = t & 63, w = t >> 6;
  const int b0 = blockIdx.x * 4;
  float acc[4];
  const float bias = k_b2[t];
#pragma unroll
  for (int r = 0; r < 4; ++r) acc[r] = bias;
#pragma unroll 4
  for (int k = 0; k < 512; ++k) {
    const float wv = k_w2[k * 128 + t];
#pragma unroll
    for (int r = 0; r < 4; ++r)
      acc[r] += henc[(size_t)(b0 + r) * 512 + k] * wv;
  }
  // sum of squares across 128 threads
  float ss[4];
#pragma unroll
  for (int r = 0; r < 4; ++r) ss[r] = acc[r] * acc[r];
#pragma unroll
  for (int off = 32; off > 0; off >>= 1)
#pragma unroll
    for (int r = 0; r < 4; ++r) ss[r] += __shfl_down(ss[r], off);
  if (l == 0)
#pragma unroll
    for (int r = 0; r < 4; ++r) s_part[w][r] = ss[r];
  __syncthreads();
#pragma unroll
  for (int r = 0; r < 4; ++r) {
    float rn = 1.0f / fmaxf(sqrtf(s_part[0][r] + s_part[1][r]), 1e-8f);
    float q = acc[r] * rn;
    qn[(size_t)(b0 + r) * K_SZ + t] = q;
    qnb[(size_t)(b0 + r) * K_SZ + t] = f2bf(q);
  }
}

// ---------------------------------------------------------------------------
// keyprep: normalized bf16 keys (PRE-SWIZZLED) + reciprocal norms.
// ---------------------------------------------------------------------------
__global__ void mann_keyprep(const float* __restrict__ keys,
                             unsigned short* __restrict__ knbsw,
                             float* __restrict__ rnk) {
  const int lane = threadIdx.x & 63;
  const int row = blockIdx.x * 4 + (threadIdx.x >> 6);
  const float* kr = keys + (size_t)row * K_SZ;
  float a = kr[lane], c = kr[lane + 64];
  float s = a * a + c * c;
#pragma unroll
  for (int off = 32; off > 0; off >>= 1) s += __shfl_down(s, off);
  float rn = 1.0f / fmaxf(sqrtf(__shfl(s, 0)), 1e-8f);
  if (lane == 0) rnk[row] = rn;
  const int r7 = row & 7;
  const int c1 = lane >> 3, j = lane & 7;
  unsigned short* base = knbsw + (size_t)row * 128;
  base[(c1 ^ r7) * 8 + j] = f2bf(a * rn);
  base[(8 | (c1 ^ r7)) * 8 + j] = f2bf(c * rn);
}

// ---------------------------------------------------------------------------
// sims: bf16 MFMA + streaming per-thread top-3 candidates (unchanged, works)
// ---------------------------------------------------------------------------
__global__ __launch_bounds__(256, 2)
void mann_sims_mfma(const unsigned short* __restrict__ qnb,
                    const unsigned short* __restrict__ knbsw,
                    unsigned* __restrict__ cand) {
  __shared__ unsigned short s_k[2 * STG * 128];
  const int t = threadIdx.x;
  const int w = t >> 6, l = t & 63;
  const int lo = l & 15, g = l >> 4;
  const int chunk = blockIdx.x, bt = blockIdx.y;
  const int b0 = bt * BT + w * 32;
  const int k0 = chunk * CH;

  short8 afrag[2][4];
#pragma unroll
  for (int rti = 0; rti < 2; ++rti)
#pragma unroll
    for (int ks = 0; ks < 4; ++ks)
      afrag[rti][ks] = *(const short8*)(qnb + (size_t)(b0 + rti * 16 + lo) * K_SZ + ks * 32 + g * 8);

  float tv[2][4][3];
  int ti[2][4][3];
#pragma unroll
  for (int a = 0; a < 2; ++a)
#pragma unroll
    for (int b = 0; b < 4; ++b)
#pragma unroll
      for (int c = 0; c < 3; ++c) { tv[a][b][c] = NEG_INF; ti[a][b][c] = 0; }
  float thr[2] = {NEG_INF, NEG_INF};

  const int ev = lo * 256 + ((g ^ (lo & 7)) << 4);
  const int od = ev ^ 64;

  const char* gbase = (const char*)knbsw + (size_t)k0 * 256;
  char* lds0 = (char*)s_k;

#define ISSUE_STAGE(S, BUF)                                                  \
  do {                                                                       \
    const char* g0 = gbase + (size_t)(S) * 16384;                            \
    char* l0 = lds0 + (BUF) * 16384;                                         \
    _Pragma("unroll")                                                        \
    for (int i = 0; i < 4; ++i) {                                            \
      int seg = i * 4 + w;                                                   \
      gl_lds16(g0 + seg * 1024 + l * 16, l0 + seg * 1024);                   \
    }                                                                        \
  } while (0)

  ISSUE_STAGE(0, 0);

  for (int s = 0; s < NSTG; ++s) {
    const int buf = s & 1;
    __syncthreads();
    if (s + 1 < NSTG) ISSUE_STAGE(s + 1, buf ^ 1);

    const int vev = ev + (buf << 14);
    const int vod = od + (buf << 14);
#pragma unroll
    for (int kt = 0; kt < 4; ++kt) {
      short8 bfrag[4];
#pragma unroll
      for (int ks = 0; ks < 4; ++ks) {
        int va = (ks & 1) ? vod : vev;
        bfrag[ks] = *(const short8*)((const char*)s_k + va + kt * 4096 + ((ks & 2) ? 128 : 0));
      }
      const int kidx = s * STG + kt * 16 + lo;
#pragma unroll
      for (int rti = 0; rti < 2; ++rti) {
        f32x4 c = {0.f, 0.f, 0.f, 0.f};
#pragma unroll
        for (int ks = 0; ks < 4; ++ks)
          c = __builtin_amdgcn_mfma_f32_16x16x32_bf16(afrag[rti][ks], bfrag[ks], c, 0, 0, 0);
        float mx = fmaxf(fmaxf(c[0], c[1]), fmaxf(c[2], c[3]));
        if (mx > thr[rti]) {
          ins3f(tv[rti][0], ti[rti][0], c[0], kidx);
          ins3f(tv[rti][1], ti[rti][1], c[1], kidx);
          ins3f(tv[rti][2], ti[rti][2], c[2], kidx);
          ins3f(tv[rti][3], ti[rti][3], c[3], kidx);
          thr[rti] = fminf(fminf(tv[rti][0][2], tv[rti][1][2]),
                           fminf(tv[rti][2][2], tv[rti][3][2]));
        }
      }
    }
  }
#undef ISSUE_STAGE

#pragma unroll
  for (int rti = 0; rti < 2; ++rti) {
#pragma unroll
    for (int j = 0; j < 4; ++j) {
      int b = b0 + rti * 16 + g * 4 + j;
      size_t base = (((size_t)b * NCH + chunk) * 16 + lo) * 3;
#pragma unroll
      for (int slot = 0; slot < 3; ++slot) {
        unsigned p = (flipbf(f2bf(tv[rti][j][slot])) << 16) | (unsigned)(ti[rti][j][slot] & 0xFFF);
        cand[base + slot] = p;
      }
    }
  }
}

// ---------------------------------------------------------------------------
// merge: candidates -> approx top-8 -> exact fp32 rescore -> top-3 (unchanged)
// ---------------------------------------------------------------------------
__global__ void mann_merge_rescore(const unsigned* __restrict__ cand,
                                   const float* __restrict__ qn,
                                   const float* __restrict__ keys,
                                   const float* __restrict__ rnk,
                                   float* __restrict__ tval,
                                   int* __restrict__ tidx) {
  __shared__ unsigned s_pv[4][192];
  __shared__ int s_gi[4][192];
  __shared__ float s_ex[4][8];
  const int t = threadIdx.x;
  const int w = t >> 6, l = t & 63;
  const int b = blockIdx.x * 4 + w;
  const int NCAND = NCH * 16 * 3;

  unsigned pv[3] = {0u, 0u, 0u};
  int gi[3] = {0, 0, 0};
  for (int k = 0; k < NCAND / 64; ++k) {
    int i = l + k * 64;
    unsigned p = cand[(size_t)b * NCAND + i];
    int gidx = (i / 48) * CH + (int)(p & 0xFFFu);
    ins3u(pv, gi, p, gidx);
  }
#pragma unroll
  for (int j = 0; j < 3; ++j) { s_pv[w][l * 3 + j] = pv[j]; s_gi[w][l * 3 + j] = gi[j]; }
  __syncthreads();

  if (l == 0) {
    unsigned bv[8]; int bg[8];
#pragma unroll
    for (int j = 0; j < 8; ++j) { bv[j] = 0u; bg[j] = 0; }
    for (int i = 0; i < 192; ++i) {
      unsigned p = s_pv[w][i];
      if (p > bv[7]) {
        int gg = s_gi[w][i];
        int j = 7;
        while (j > 0 && p > bv[j - 1]) { bv[j] = bv[j - 1]; bg[j] = bg[j - 1]; --j; }
        bv[j] = p; bg[j] = gg;
      }
    }
#pragma unroll
    for (int j = 0; j < 8; ++j) s_gi[w][j] = bg[j];
  }
  __syncthreads();

  float q0 = qn[(size_t)b * K_SZ + l];
  float q1 = qn[(size_t)b * K_SZ + 64 + l];
#pragma unroll
  for (int d = 0; d < 8; ++d) {
    int idx = s_gi[w][d];
    float p = q0 * keys[(size_t)idx * K_SZ + l] + q1 * keys[(size_t)idx * K_SZ + 64 + l];
#pragma unroll
    for (int off = 32; off > 0; off >>= 1) p += __shfl_down(p, off);
    if (l == 0) s_ex[w][d] = p * rnk[idx];
  }
  __syncthreads();

  if (l == 0) {
    unsigned used = 0;
#pragma unroll
    for (int r = 0; r < 3; ++r) {
      float best = NEG_INF; int bd = 0;
      for (int d = 0; d < 8; ++d)
        if (!(used & (1u << d)) && s_ex[w][d] > best) { best = s_ex[w][d]; bd = d; }
      used |= (1u << bd);
      tval[b * 3 + r] = best;
      tidx[b * 3 + r] = s_gi[w][bd];
    }
  }
}

// ---------------------------------------------------------------------------
// T1: attention MLP + softmax + mem_vec.  grid (B/4); 128 thr.
// Writes mem [B][256] and hit [B].
// ---------------------------------------------------------------------------
__global__ __launch_bounds__(128)
void mann_t1(const float* __restrict__ state,
             const float* __restrict__ values,
             const float* __restrict__ tval,
             const int* __restrict__ tidx,
             const float* __restrict__ a_w1, const float* __restrict__ a_b1,
             const float* __restrict__ a_w2, const float* __restrict__ a_b2,
             float* __restrict__ mem, int* __restrict__ hit) {
  __shared__ float s_h1[12][128];
  __shared__ float s_logit[12];
  __shared__ float s_attn[4][3];
  const int t = threadIdx.x;
  const int b0 = blockIdx.x * 4;

  // state part: racc[r] shared by the row's 3 streams
  float racc[4];
  {
    const float bias = a_b1[t];
#pragma unroll
    for (int r = 0; r < 4; ++r) racc[r] = bias;
  }
#pragma unroll 4
  for (int k = 0; k < 256; ++k) {
    const float w = a_w1[k * 128 + t];
#pragma unroll
    for (int r = 0; r < 4; ++r)
      racc[r] += state[(size_t)(b0 + r) * E_SZ + k] * w;
  }
  // value part: 12 streams
  float pacc[12];
#pragma unroll
  for (int p = 0; p < 12; ++p) pacc[p] = racc[p / 3];
#pragma unroll 2
  for (int k = 0; k < 256; ++k) {
    const float w = a_w1[(256 + k) * 128 + t];
#pragma unroll
    for (int p = 0; p < 12; ++p) {
      const int vrow = tidx[(b0 + p / 3) * 3 + (p % 3)];
      pacc[p] += values[(size_t)vrow * V_SZ + k] * w;
    }
  }
#pragma unroll
  for (int p = 0; p < 12; ++p) s_h1[p][t] = tanhf(pacc[p]);
  __syncthreads();

  // logits: 12 dot-128, 8 threads each (96 threads)
  if (t < 96) {
    const int p = t >> 3, l8 = t & 7;
    float acc = 0.f;
    for (int i = l8; i < 128; i += 8)
      acc += s_h1[p][i] * a_w2[i];
#pragma unroll
    for (int off = 4; off > 0; off >>= 1) acc += __shfl_down(acc, off, 8);
    if (l8 == 0) s_logit[p] = acc + a_b2[0];
  }
  __syncthreads();

  if (t < 4) {
    const int b = b0 + t;
    bool h0 = tval[b * 3 + 0] >= 0.0f;
    bool h1 = tval[b * 3 + 1] >= 0.0f;
    bool h2 = tval[b * 3 + 2] >= 0.0f;
    float l0 = h0 ? s_logit[t * 3 + 0] : -1e9f;
    float l1 = h1 ? s_logit[t * 3 + 1] : -1e9f;
    float l2 = h2 ? s_logit[t * 3 + 2] : -1e9f;
    float mx = fmaxf(l0, fmaxf(l1, l2));
    float e0 = expf(l0 - mx), e1 = expf(l1 - mx), e2 = expf(l2 - mx);
    float inv = 1.0f / (e0 + e1 + e2);
    s_attn[t][0] = e0 * inv; s_attn[t][1] = e1 * inv; s_attn[t][2] = e2 * inv;
    hit[b] = (h0 || h1 || h2) ? 1 : 0;
  }
  __syncthreads();

  // mem_vec: 256 cols, 128 threads x 2
#pragma unroll
  for (int r = 0; r < 4; ++r) {
    const int i0 = tidx[(b0 + r) * 3 + 0];
    const int i1 = tidx[(b0 + r) * 3 + 1];
    const int i2 = tidx[(b0 + r) * 3 + 2];
    const float a0 = s_attn[r][0], a1 = s_attn[r][1], a2 = s_attn[r][2];
#pragma unroll
    for (int h = 0; h < 2; ++h) {
      const int c = t + h * 128;
      mem[(size_t)(b0 + r) * V_SZ + c] =
          a0 * values[(size_t)i0 * V_SZ + c] +
          a1 * values[(size_t)i1 * V_SZ + c] +
          a2 * values[(size_t)i2 * V_SZ + c];
    }
  }
}

// ---------------------------------------------------------------------------
// T2a: h2 = relu([state, mem] @ i_w1 + b1).  [B,512], K=512.
// grid (B/8, 2); 256 thr; thread owns 1 col of its slice, 8 rows.
// ---------------------------------------------------------------------------
__global__ __launch_bounds__(256)
void mann_t2a(const float* __restrict__ state,
              const float* __restrict__ mem,
              const float* __restrict__ i_w1, const float* __restrict__ i_b1,
              float* __restrict__ h2) {
  const int t = threadIdx.x;
  const int c = blockIdx.y * 256 + t;
  const int b0 = blockIdx.x * 8;
  float acc[8];
  const float bias = i_b1[c];
#pragma unroll
  for (int r = 0; r < 8; ++r) acc[r] = bias;
#pragma unroll 4
  for (int k = 0; k < 256; ++k) {
    const float w = i_w1[k * 512 + c];
#pragma unroll
    for (int r = 0; r < 8; ++r)
      acc[r] += state[(size_t)(b0 + r) * E_SZ + k] * w;
  }
#pragma unroll 4
  for (int k = 0; k < 256; ++k) {
    const float w = i_w1[(256 + k) * 512 + c];
#pragma unroll
    for (int r = 0; r < 8; ++r)
      acc[r] += mem[(size_t)(b0 + r) * V_SZ + k] * w;
  }
#pragma unroll
  for (int r = 0; r < 8; ++r)
    h2[(size_t)(b0 + r) * 512 + c] = fmaxf(acc[r], 0.f);
}

// ---------------------------------------------------------------------------
// T2b: out = h2 @ i_w2 + b2 (hit) else fallback MLP.  grid (B/4); 256 thr.
// ---------------------------------------------------------------------------
__global__ __launch_bounds__(256)
void mann_t2b(const float* __restrict__ h2,
              const float* __restrict__ state,
              const int* __restrict__ hit,
              const float* __restrict__ i_w2, const float* __restrict__ i_b2,
              const float* __restrict__ f_w1, const float* __restrict__ f_b1,
              const float* __restrict__ f_w2, const float* __restrict__ f_b2,
              float* __restrict__ out) {
  __shared__ float s_fh[512];
  const int t = threadIdx.x;
  const int b0 = blockIdx.x * 4;
  float acc[4];
  const float bias = i_b2[t];
#pragma unroll
  for (int r = 0; r < 4; ++r) acc[r] = bias;
#pragma unroll 4
  for (int k = 0; k < 512; ++k) {
    const float w = i_w2[k * 256 + t];
#pragma unroll
    for (int r = 0; r < 4; ++r)
      acc[r] += h2[(size_t)(b0 + r) * 512 + k] * w;
  }
#pragma unroll
  for (int r = 0; r < 4; ++r) {
    if (hit[b0 + r]) {
      out[(size_t)(b0 + r) * O_SZ + t] = acc[r];
    } else {
      // fallback (block-uniform branch; essentially never taken)
      __syncthreads();
#pragma unroll
      for (int h = 0; h < 2; ++h) {
        const int j = t + h * 256;
        float a = f_b1[j];
        for (int k = 0; k < 256; ++k)
          a += state[(size_t)(b0 + r) * E_SZ + k] * f_w1[k * 512 + j];
        s_fh[j] = fmaxf(a, 0.f);
      }
      __syncthreads();
      float o = f_b2[t];
      for (int k = 0; k < 512; ++k) o += s_fh[k] * f_w2[k * 256 + t];
      out[(size_t)(b0 + r) * O_SZ + t] = o;
    }
  }
}

// ---------------------------------------------------------------------------
extern "C" void kernel_launch(void* const* d_in, const int* in_sizes, int n_in,
                              void* d_out, int out_size, void* d_ws, size_t ws_size,
                              hipStream_t stream) {
  const float* state = (const float*)d_in[0];
  const float* keys  = (const float*)d_in[1];
  const float* values = (const float*)d_in[2];
  const float* k_w1 = (const float*)d_in[3];
  const float* k_b1 = (const float*)d_in[4];
  const float* k_w2 = (const float*)d_in[5];
  const float* k_b2 = (const float*)d_in[6];
  const float* a_w1 = (const float*)d_in[7];
  const float* a_b1 = (const float*)d_in[8];
  const float* a_w2 = (const float*)d_in[9];
  const float* a_b2 = (const float*)d_in[10];
  const float* i_w1 = (const float*)d_in[11];
  const float* i_b1 = (const float*)d_in[12];
  const float* i_w2 = (const float*)d_in[13];
  const float* i_b2 = (const float*)d_in[14];
  const float* f_w1 = (const float*)d_in[15];
  const float* f_b1 = (const float*)d_in[16];
  const float* f_w2 = (const float*)d_in[17];
  const float* f_b2 = (const float*)d_in[18];
  float* out = (float*)d_out;

  float* ws = (float*)d_ws;
  float* qn = ws + WS_QN;
  unsigned short* qnb = (unsigned short*)(ws + WS_QNB);
  unsigned short* knbsw = (unsigned short*)(ws + WS_KNB);
  float* rnk = ws + WS_RNK;
  unsigned* cand = (unsigned*)(ws + WS_CAND);
  float* tvalp = ws + WS_TVAL;
  int* tidxp = (int*)(ws + WS_TIDX);
  float* henc = ws + WS_HENC;
  float* memv = ws + WS_MEM;
  float* h2 = ws + WS_H2;
  int* hitp = (int*)(ws + WS_HIT);

  mann_enc1<<<dim3(B_SZ / 8, 2), 256, 0, stream>>>(state, k_w1, k_b1, henc);
  mann_enc2<<<B_SZ / 4, 128, 0, stream>>>(henc, k_w2, k_b2, qn, qnb);
  mann_keyprep<<<M_SZ / 4, 256, 0, stream>>>(keys, knbsw, rnk);
  mann_sims_mfma<<<dim3(NCH, B_SZ / BT), 256, 0, stream>>>(qnb, knbsw, cand);
  mann_merge_rescore<<<B_SZ / 4, 256, 0, stream>>>(cand, qn, keys, rnk, tvalp, tidxp);
  mann_t1<<<B_SZ / 4, 128, 0, stream>>>(state, values, tvalp, tidxp,
                                        a_w1, a_b1, a_w2, a_b2, memv, hitp);
  mann_t2a<<<dim3(B_SZ / 8, 2), 256, 0, stream>>>(state, memv, i_w1, i_b1, h2);
  mann_t2b<<<B_SZ / 4, 256, 0, stream>>>(h2, state, hitp, i_w2, i_b2,
                                         f_w1, f_b1, f_w2, f_b2, out);
}